// Round 1
// baseline (5442.842 us; speedup 1.0000x reference)
//
#include <hip/hip_runtime.h>
#include <math.h>

#define BN_INVF 0.9999950000374998f
#define LN_EPSF 1e-5f

// ---------------- small helpers ----------------

__device__ inline float block_sum256(float v, float* sbuf) {
    for (int off = 32; off; off >>= 1) v += __shfl_down(v, off);
    int lane = threadIdx.x & 63, w = threadIdx.x >> 6;
    if (lane == 0) sbuf[w] = v;
    __syncthreads();
    float r;
    if (threadIdx.x == 0) { r = sbuf[0] + sbuf[1] + sbuf[2] + sbuf[3]; sbuf[0] = r; }
    __syncthreads();
    r = sbuf[0];
    __syncthreads();
    return r;
}

__device__ inline unsigned long long shfl_down_u64(unsigned long long v, int off) {
    unsigned lo = (unsigned)v, hi = (unsigned)(v >> 32);
    lo = __shfl_down(lo, off); hi = __shfl_down(hi, off);
    return ((unsigned long long)hi << 32) | lo;
}

__device__ inline unsigned fkey(float v) {
    unsigned u = __float_as_uint(v);
    return (u & 0x80000000u) ? ~u : (u | 0x80000000u);
}

// ---------------- kernels ----------------

// x (2,2048,3) -> xT (2,3,2048)
__global__ void transpose_x_kernel(const float* __restrict__ x, float* __restrict__ xT) {
    int i = blockIdx.x * blockDim.x + threadIdx.x;
    if (i >= 2 * 3 * 2048) return;
    int b = i / (3 * 2048), r = i % (3 * 2048), c = r / 2048, n = r % 2048;
    xT[i] = x[(b * 2048 + n) * 3 + c];
}

// xx[b,n] = sum_c x[b,c,n]^2 ; x has channel stride 2048, batch stride bstr
__global__ void xx_kernel(const float* __restrict__ x, float* __restrict__ xx, int C, long long bstr) {
    int i = blockIdx.x * blockDim.x + threadIdx.x;
    if (i >= 2 * 2048) return;
    int b = i / 2048, n = i % 2048;
    const float* p = x + (long long)b * bstr + n;
    float s = 0.f;
    for (int c = 0; c < C; c++) { float v = p[(long long)c * 2048]; s = fmaf(v, v, s); }
    xx[i] = s;
}

// Generic tiled SGEMM: C = A @ B, 64x64 tile, epilogue modes:
// 0: plain   1: lrelu(vrow[m]*(acc*BN_INV)+vrow[M+m])
// 2: gelu(acc+vcol[n])   3: acc+vcol[n]+res   4: 2*acc - xx[m] - xx[n] (vrow=xx, batch stride M)
__launch_bounds__(256)
__global__ void gemm_kernel(const float* __restrict__ A, const float* __restrict__ Bm,
                            float* __restrict__ Cm, const float* __restrict__ res,
                            const float* __restrict__ vrow, const float* __restrict__ vcol,
                            int M, int N, int Kd, int lda, int ldb, int ldc,
                            long long sA, long long sB, long long sC,
                            int transA, int mode) {
    int tid = threadIdx.x;
    int tx = tid & 15, ty = tid >> 4;
    int m0 = blockIdx.y * 64, n0 = blockIdx.x * 64;
    A  += (long long)blockIdx.z * sA;
    Bm += (long long)blockIdx.z * sB;
    Cm += (long long)blockIdx.z * sC;
    const float* resb = res ? res + (long long)blockIdx.z * sC : nullptr;

    __shared__ float As[16][64];
    __shared__ float Bs[16][64];
    float acc[4][4] = {};

    for (int k0 = 0; k0 < Kd; k0 += 16) {
#pragma unroll
        for (int e = 0; e < 4; e++) {
            int i = tid + e * 256;
            int kk, mm;
            if (transA) { mm = i & 63; kk = i >> 6; } else { kk = i & 15; mm = i >> 4; }
            int gm = m0 + mm, gk = k0 + kk;
            float v = 0.f;
            if (gm < M && gk < Kd)
                v = transA ? A[(long long)gk * lda + gm] : A[(long long)gm * lda + gk];
            As[kk][mm] = v;
        }
#pragma unroll
        for (int e = 0; e < 4; e++) {
            int i = tid + e * 256;
            int nn = i & 63, kk = i >> 6;
            int gk = k0 + kk, gn = n0 + nn;
            float v = 0.f;
            if (gk < Kd && gn < N) v = Bm[(long long)gk * ldb + gn];
            Bs[kk][nn] = v;
        }
        __syncthreads();
#pragma unroll
        for (int kk = 0; kk < 16; kk++) {
            float4 av = *(const float4*)&As[kk][ty * 4];
            float4 bv = *(const float4*)&Bs[kk][tx * 4];
            float a4[4] = {av.x, av.y, av.z, av.w};
            float b4[4] = {bv.x, bv.y, bv.z, bv.w};
#pragma unroll
            for (int i = 0; i < 4; i++)
#pragma unroll
                for (int j = 0; j < 4; j++)
                    acc[i][j] = fmaf(a4[i], b4[j], acc[i][j]);
        }
        __syncthreads();
    }

    const float* xxb = (mode == 4) ? vrow + (long long)blockIdx.z * M : nullptr;
#pragma unroll
    for (int i = 0; i < 4; i++) {
        int m = m0 + ty * 4 + i;
        if (m >= M) continue;
#pragma unroll
        for (int j = 0; j < 4; j++) {
            int n = n0 + tx * 4 + j;
            if (n >= N) continue;
            float v = acc[i][j];
            if (mode == 1) {
                v = vrow[m] * (v * BN_INVF) + vrow[M + m];
                v = v > 0.f ? v : 0.2f * v;
            } else if (mode == 2) {
                v += vcol[n];
                v = 0.5f * v * (1.f + erff(v * 0.70710678118654752f));
            } else if (mode == 3) {
                v += vcol[n];
                v += resb[(long long)m * ldc + n];
            } else if (mode == 4) {
                v = 2.f * v - xxb[m] - xxb[n];
            }
            Cm[(long long)m * ldc + n] = v;
        }
    }
}

// top-20 (largest, lower-index tie-break) per row of pd (4096 rows x 2048)
__global__ void topk_kernel(const float* __restrict__ pd, int* __restrict__ idxo) {
    int row = blockIdx.x;
    const float* p = pd + (long long)row * 2048;
    int tid = threadIdx.x;
    float vals[8];
#pragma unroll
    for (int j = 0; j < 8; j++) vals[j] = p[tid + j * 256];
    __shared__ unsigned long long sred[4];
    __shared__ int swin;
    int* out = idxo + (long long)row * 20;
    for (int k = 0; k < 20; k++) {
        float bv = vals[0]; int bj = 0;
#pragma unroll
        for (int j = 1; j < 8; j++) if (vals[j] > bv) { bv = vals[j]; bj = j; }
        int m = tid + bj * 256;
        unsigned long long pk = ((unsigned long long)fkey(bv) << 32) | (unsigned)(2048 - m);
        for (int off = 32; off; off >>= 1) {
            unsigned long long o2 = shfl_down_u64(pk, off);
            if (o2 > pk) pk = o2;
        }
        if ((tid & 63) == 0) sred[tid >> 6] = pk;
        __syncthreads();
        if (tid == 0) {
            unsigned long long best = sred[0];
            for (int w = 1; w < 4; w++) if (sred[w] > best) best = sred[w];
            int mwin = 2048 - (int)(best & 0xffffffffu);
            swin = mwin;
            out[k] = mwin;
        }
        __syncthreads();
        int mwin = swin;
        if ((mwin & 255) == tid) vals[mwin >> 8] = -3.0e38f;
        __syncthreads();
    }
}

// wcat (2O x C): rows 0..O-1 = w[:, :C]; rows O..2O-1 = w[:, C:] - w[:, :C]
__global__ void wcat_kernel(const float* __restrict__ w, float* __restrict__ wcat, int O, int C) {
    int i = blockIdx.x * blockDim.x + threadIdx.x;
    if (i >= 2 * O * C) return;
    int o2 = i / C, c = i % C;
    if (o2 < O) wcat[i] = w[o2 * 2 * C + c];
    else { int o = o2 - O; wcat[i] = w[o * 2 * C + C + c] - w[o * 2 * C + c]; }
}

// out[b,o,n] = max_k lrelu(bn( Y[b,o,idx[b,n,k]] + Y[b,O+o,n] ))
__global__ void gather_max_kernel(const float* __restrict__ Y, const int* __restrict__ idx,
                                  const float* __restrict__ bn, float* __restrict__ out, int O) {
    int i = blockIdx.x * blockDim.x + threadIdx.x;
    int total = 2 * O * 2048;
    if (i >= total) return;
    int b = i / (O * 2048), r = i % (O * 2048), o = r / 2048, n = r % 2048;
    const float* Arow = Y + ((long long)b * 2 * O + o) * 2048;
    float bc = Y[((long long)b * 2 * O + O + o) * 2048 + n];
    float sc = bn[o], sh = bn[O + o];
    const int* ip = idx + ((long long)b * 2048 + n) * 20;
    float best = -3.0e38f;
#pragma unroll
    for (int k = 0; k < 20; k++) {
        int m = ip[k];
        float y = Arow[m] + bc;
        float v = sc * (y * BN_INVF) + sh;
        v = v > 0.f ? v : 0.2f * v;
        best = fmaxf(best, v);
    }
    out[(long long)b * (512 * 2048) + (long long)o * 2048 + n] = best;
}

// h[b,1+p,o] = max over 32 points of y5[b,o,32p+i]
__global__ void pool_kernel(const float* __restrict__ y5, float* __restrict__ h) {
    int i = blockIdx.x * blockDim.x + threadIdx.x;
    if (i >= 2 * 64 * 1024) return;
    int b = i / (64 * 1024), r = i % (64 * 1024), p = r / 1024, o = r % 1024;
    const float* src = y5 + ((long long)b * 1024 + o) * 2048 + p * 32;
    float mx = src[0];
#pragma unroll
    for (int j = 1; j < 32; j++) mx = fmaxf(mx, src[j]);
    h[((long long)b * 65 + 1 + p) * 1024 + o] = mx;
}

__global__ void cls_kernel(const float* __restrict__ cls, float* __restrict__ h) {
    int i = blockIdx.x * blockDim.x + threadIdx.x;
    if (i >= 2 * 1024) return;
    int b = i / 1024, d = i % 1024;
    h[(long long)(b * 65) * 1024 + d] = cls[d];
}

__global__ void addpos_kernel(float* __restrict__ h, const float* __restrict__ pos) {
    int i = blockIdx.x * blockDim.x + threadIdx.x;
    if (i >= 2 * 65 * 1024) return;
    h[i] += pos[i];
}

// layernorm per row of 1024
__global__ void ln_kernel(const float* __restrict__ xin, const float* __restrict__ g,
                          const float* __restrict__ bta, float* __restrict__ out) {
    __shared__ float sbuf[4];
    int row = blockIdx.x;
    const float* x = xin + (long long)row * 1024;
    float* o = out + (long long)row * 1024;
    float loc[4];
    float s = 0.f;
#pragma unroll
    for (int i = 0; i < 4; i++) { loc[i] = x[threadIdx.x + i * 256]; s += loc[i]; }
    float mean = block_sum256(s, sbuf) * (1.f / 1024.f);
    float s2 = 0.f;
#pragma unroll
    for (int i = 0; i < 4; i++) { float d = loc[i] - mean; s2 = fmaf(d, d, s2); }
    float var = block_sum256(s2, sbuf) * (1.f / 1024.f);
    float inv = rsqrtf(var + LN_EPSF);
#pragma unroll
    for (int i = 0; i < 4; i++) {
        int d = threadIdx.x + i * 256;
        o[d] = (loc[i] - mean) * inv * g[d] + bta[d];
    }
}

// one block per (l, head, b); qkv (B,65,1536) packed [q|k|v] with head-major 64
__global__ void attn_kernel(const float* __restrict__ qkv, float* __restrict__ z) {
    int l = blockIdx.x, hh = blockIdx.y, b = blockIdx.z;
    __shared__ float qs[64];
    __shared__ float sc[65];
    __shared__ float sred[2];
    int tid = threadIdx.x;
    const float* base = qkv + (long long)b * 65 * 1536;
    if (tid < 64) qs[tid] = base[(long long)l * 1536 + hh * 64 + tid];
    __syncthreads();
    if (tid < 65) {
        const float* kp = base + (long long)tid * 1536 + 512 + hh * 64;
        float d = 0.f;
#pragma unroll
        for (int c = 0; c < 64; c++) d = fmaf(qs[c], kp[c], d);
        sc[tid] = d * 0.125f;
    }
    __syncthreads();
    if (tid == 0) { float mx = sc[0]; for (int i = 1; i < 65; i++) mx = fmaxf(mx, sc[i]); sred[0] = mx; }
    __syncthreads();
    if (tid < 65) sc[tid] = expf(sc[tid] - sred[0]);
    __syncthreads();
    if (tid == 0) { float sm = 0.f; for (int i = 0; i < 65; i++) sm += sc[i]; sred[1] = sm; }
    __syncthreads();
    if (tid < 65) sc[tid] = sc[tid] / sred[1];
    __syncthreads();
    if (tid < 64) {
        float a = 0.f;
        const float* vp = base + 1024 + hh * 64 + tid;
        for (int m = 0; m < 65; m++) a = fmaf(sc[m], vp[(long long)m * 1536], a);
        z[((long long)b * 65 + l) * 512 + hh * 64 + tid] = a;
    }
}

__global__ void outcopy_kernel(const float* __restrict__ h, float* __restrict__ out) {
    int i = blockIdx.x * blockDim.x + threadIdx.x;
    if (i >= 2 * 64 * 1024) return;
    int b = i / (64 * 1024), r = i % (64 * 1024);
    out[i] = h[((long long)b * 65 + 1) * 1024 + r];
}

// ---------------- host side ----------------

static void graph_layer(hipStream_t stream, const float* xin, long long xin_bstr, int C,
                        const float* w, const float* bn, int O,
                        float* xxb, float* pdb, int* idxb, float* wcatb, float* Yb,
                        float* outp) {
    xx_kernel<<<(2 * 2048 + 255) / 256, 256, 0, stream>>>(xin, xxb, C, xin_bstr);
    {
        dim3 g(2048 / 64, 2048 / 64, 2);
        gemm_kernel<<<g, 256, 0, stream>>>(xin, xin, pdb, nullptr, xxb, nullptr,
                                           2048, 2048, C, 2048, 2048, 2048,
                                           xin_bstr, xin_bstr, (long long)2048 * 2048,
                                           1, 4);
    }
    topk_kernel<<<2 * 2048, 256, 0, stream>>>(pdb, idxb);
    wcat_kernel<<<(2 * O * C + 255) / 256, 256, 0, stream>>>(w, wcatb, O, C);
    {
        dim3 g(2048 / 64, (2 * O + 63) / 64, 2);
        gemm_kernel<<<g, 256, 0, stream>>>(wcatb, xin, Yb, nullptr, nullptr, nullptr,
                                           2 * O, 2048, C, C, 2048, 2048,
                                           0, xin_bstr, (long long)2 * O * 2048,
                                           0, 0);
    }
    gather_max_kernel<<<(2 * O * 2048 + 255) / 256, 256, 0, stream>>>(Yb, idxb, bn, outp, O);
}

extern "C" void kernel_launch(void* const* d_in, const int* in_sizes, int n_in,
                              void* d_out, int out_size, void* d_ws, size_t ws_size,
                              hipStream_t stream) {
    const float* x    = (const float*)d_in[0];
    const float* pos  = (const float*)d_in[1];
    const float* cls  = (const float*)d_in[2];
    const float* w1   = (const float*)d_in[3];
    const float* bn1  = (const float*)d_in[4];
    const float* w2   = (const float*)d_in[5];
    const float* bn2  = (const float*)d_in[6];
    const float* w3   = (const float*)d_in[7];
    const float* bn3  = (const float*)d_in[8];
    const float* w4   = (const float*)d_in[9];
    const float* bn4  = (const float*)d_in[10];
    const float* w5   = (const float*)d_in[11];
    const float* bn5  = (const float*)d_in[12];
    const float* ln1  = (const float*)d_in[13];
    const float* wqkv = (const float*)d_in[14];
    const float* wo   = (const float*)d_in[15];
    const float* bo   = (const float*)d_in[16];
    const float* ln2  = (const float*)d_in[17];
    const float* wf1  = (const float*)d_in[18];
    const float* bf1  = (const float*)d_in[19];
    const float* wf2  = (const float*)d_in[20];
    const float* bf2  = (const float*)d_in[21];
    float* outp = (float*)d_out;

    size_t off = 0;
    auto alloc = [&](size_t nbytes) {
        size_t p = off;
        off += (nbytes + 255) & ~(size_t)255;
        return p;
    };
    char* ws = (char*)d_ws;
    float* xT   = (float*)(ws + alloc((size_t)2 * 3 * 2048 * 4));
    float* xxb  = (float*)(ws + alloc((size_t)2 * 2048 * 4));
    int*   idxb = (int*)  (ws + alloc((size_t)2 * 2048 * 20 * 4));
    float* pdb  = (float*)(ws + alloc((size_t)2 * 2048 * 2048 * 4));   // reused as y5
    float* wcatb= (float*)(ws + alloc((size_t)512 * 128 * 4));
    float* Yb   = (float*)(ws + alloc((size_t)2 * 512 * 2048 * 4));
    float* xcat = (float*)(ws + alloc((size_t)2 * 512 * 2048 * 4));
    float* hbuf = (float*)(ws + alloc((size_t)2 * 65 * 1024 * 4));
    float* tbuf = (float*)(ws + alloc((size_t)2 * 65 * 1024 * 4));
    float* qkvb = (float*)(ws + alloc((size_t)2 * 65 * 1536 * 4));
    float* zbuf = (float*)(ws + alloc((size_t)2 * 65 * 512 * 4));
    float* midb = (float*)(ws + alloc((size_t)2 * 65 * 2048 * 4));
    (void)ws_size; (void)in_sizes; (void)n_in; (void)out_size;

    // ---- DGCNN patch embed ----
    transpose_x_kernel<<<(2 * 3 * 2048 + 255) / 256, 256, 0, stream>>>(x, xT);

    long long cbs = (long long)512 * 2048;  // xcat batch stride
    graph_layer(stream, xT,                (long long)3 * 2048, 3,   w1, bn1, 64,  xxb, pdb, idxb, wcatb, Yb, xcat + 0);
    graph_layer(stream, xcat + 0,          cbs,                 64,  w2, bn2, 64,  xxb, pdb, idxb, wcatb, Yb, xcat + (long long)64 * 2048);
    graph_layer(stream, xcat + (long long)64 * 2048,  cbs,      64,  w3, bn3, 128, xxb, pdb, idxb, wcatb, Yb, xcat + (long long)128 * 2048);
    graph_layer(stream, xcat + (long long)128 * 2048, cbs,      128, w4, bn4, 256, xxb, pdb, idxb, wcatb, Yb, xcat + (long long)256 * 2048);

    // conv5: y5 = lrelu(bn5(w5 @ xcat)), y5 aliases pdb
    float* y5 = pdb;
    {
        dim3 g(2048 / 64, 1024 / 64, 2);
        gemm_kernel<<<g, 256, 0, stream>>>(w5, xcat, y5, nullptr, bn5, nullptr,
                                           1024, 2048, 512, 512, 2048, 2048,
                                           0, cbs, (long long)1024 * 2048, 0, 1);
    }
    pool_kernel<<<(2 * 64 * 1024 + 255) / 256, 256, 0, stream>>>(y5, hbuf);
    cls_kernel<<<(2 * 1024 + 255) / 256, 256, 0, stream>>>(cls, hbuf);

    // ---- transformer ----
    for (int L = 0; L < 6; L++) {
        const float* ln1g = ln1 + (long long)L * 2048;
        const float* ln2g = ln2 + (long long)L * 2048;
        const float* wqkvL = wqkv + (long long)L * 1024 * 1536;
        const float* woL   = wo   + (long long)L * 512 * 1024;
        const float* boL   = bo   + (long long)L * 1024;
        const float* wf1L  = wf1  + (long long)L * 1024 * 2048;
        const float* bf1L  = bf1  + (long long)L * 2048;
        const float* wf2L  = wf2  + (long long)L * 2048 * 1024;
        const float* bf2L  = bf2  + (long long)L * 1024;

        addpos_kernel<<<(2 * 65 * 1024 + 255) / 256, 256, 0, stream>>>(hbuf, pos);
        ln_kernel<<<130, 256, 0, stream>>>(hbuf, ln1g, ln1g + 1024, tbuf);
        {   // qkv = t @ wqkv
            dim3 g(1536 / 64, 2, 2);
            gemm_kernel<<<g, 256, 0, stream>>>(tbuf, wqkvL, qkvb, nullptr, nullptr, nullptr,
                                               65, 1536, 1024, 1024, 1536, 1536,
                                               (long long)65 * 1024, 0, (long long)65 * 1536, 0, 0);
        }
        attn_kernel<<<dim3(65, 8, 2), 128, 0, stream>>>(qkvb, zbuf);
        {   // h = h + z @ wo + bo
            dim3 g(1024 / 64, 2, 2);
            gemm_kernel<<<g, 256, 0, stream>>>(zbuf, woL, hbuf, hbuf, nullptr, boL,
                                               65, 1024, 512, 512, 1024, 1024,
                                               (long long)65 * 512, 0, (long long)65 * 1024, 0, 3);
        }
        ln_kernel<<<130, 256, 0, stream>>>(hbuf, ln2g, ln2g + 1024, tbuf);
        {   // mid = gelu(t @ wf1 + bf1)
            dim3 g(2048 / 64, 2, 2);
            gemm_kernel<<<g, 256, 0, stream>>>(tbuf, wf1L, midb, nullptr, nullptr, bf1L,
                                               65, 2048, 1024, 1024, 2048, 2048,
                                               (long long)65 * 1024, 0, (long long)65 * 2048, 0, 2);
        }
        {   // h = h + mid @ wf2 + bf2
            dim3 g(1024 / 64, 2, 2);
            gemm_kernel<<<g, 256, 0, stream>>>(midb, wf2L, hbuf, hbuf, nullptr, bf2L,
                                               65, 1024, 2048, 2048, 1024, 1024,
                                               (long long)65 * 2048, 0, (long long)65 * 1024, 0, 3);
        }
    }

    outcopy_kernel<<<(2 * 64 * 1024 + 255) / 256, 256, 0, stream>>>(hbuf, outp);
}

// Round 2
// 1556.461 us; speedup vs baseline: 3.4969x; 3.4969x over previous
//
#include <hip/hip_runtime.h>
#include <math.h>

#define BN_INVF 0.9999950000374998f
#define LN_EPSF 1e-5f

// ---------------- small helpers ----------------

__device__ inline float block_sum256(float v, float* sbuf) {
    for (int off = 32; off; off >>= 1) v += __shfl_down(v, off);
    int lane = threadIdx.x & 63, w = threadIdx.x >> 6;
    if (lane == 0) sbuf[w] = v;
    __syncthreads();
    float r;
    if (threadIdx.x == 0) { r = sbuf[0] + sbuf[1] + sbuf[2] + sbuf[3]; sbuf[0] = r; }
    __syncthreads();
    r = sbuf[0];
    __syncthreads();
    return r;
}

__device__ inline unsigned long long shfl_down_u64(unsigned long long v, int off) {
    unsigned lo = (unsigned)v, hi = (unsigned)(v >> 32);
    lo = __shfl_down(lo, off); hi = __shfl_down(hi, off);
    return ((unsigned long long)hi << 32) | lo;
}

__device__ inline unsigned fkey(float v) {
    unsigned u = __float_as_uint(v);
    return (u & 0x80000000u) ? ~u : (u | 0x80000000u);
}

// ---------------- kernels ----------------

// x (2,2048,3) -> xT (2,3,2048)
__global__ void transpose_x_kernel(const float* __restrict__ x, float* __restrict__ xT) {
    int i = blockIdx.x * blockDim.x + threadIdx.x;
    if (i >= 2 * 3 * 2048) return;
    int b = i / (3 * 2048), r = i % (3 * 2048), c = r / 2048, n = r % 2048;
    xT[i] = x[(b * 2048 + n) * 3 + c];
}

// xx[b,n] = sum_c x[b,c,n]^2 ; x has channel stride 2048, batch stride bstr
__global__ void xx_kernel(const float* __restrict__ x, float* __restrict__ xx, int C, long long bstr) {
    int i = blockIdx.x * blockDim.x + threadIdx.x;
    if (i >= 2 * 2048) return;
    int b = i / 2048, n = i % 2048;
    const float* p = x + (long long)b * bstr + n;
    float s = 0.f;
    for (int c = 0; c < C; c++) { float v = p[(long long)c * 2048]; s = fmaf(v, v, s); }
    xx[i] = s;
}

// Generic tiled SGEMM: C = A @ B, 64x64 tile, epilogue modes:
// 0: plain   1: lrelu(vrow[m]*(acc*BN_INV)+vrow[M+m])
// 4: 2*acc - xx[m] - xx[n] (vrow=xx, batch stride M)
__launch_bounds__(256)
__global__ void gemm_kernel(const float* __restrict__ A, const float* __restrict__ Bm,
                            float* __restrict__ Cm,
                            const float* __restrict__ vrow,
                            int M, int N, int Kd, int lda, int ldb, int ldc,
                            long long sA, long long sB, long long sC,
                            int transA, int mode) {
    int tid = threadIdx.x;
    int tx = tid & 15, ty = tid >> 4;
    int m0 = blockIdx.y * 64, n0 = blockIdx.x * 64;
    A  += (long long)blockIdx.z * sA;
    Bm += (long long)blockIdx.z * sB;
    Cm += (long long)blockIdx.z * sC;

    __shared__ float As[16][64];
    __shared__ float Bs[16][64];
    float acc[4][4] = {};

    for (int k0 = 0; k0 < Kd; k0 += 16) {
#pragma unroll
        for (int e = 0; e < 4; e++) {
            int i = tid + e * 256;
            int kk, mm;
            if (transA) { mm = i & 63; kk = i >> 6; } else { kk = i & 15; mm = i >> 4; }
            int gm = m0 + mm, gk = k0 + kk;
            float v = 0.f;
            if (gm < M && gk < Kd)
                v = transA ? A[(long long)gk * lda + gm] : A[(long long)gm * lda + gk];
            As[kk][mm] = v;
        }
#pragma unroll
        for (int e = 0; e < 4; e++) {
            int i = tid + e * 256;
            int nn = i & 63, kk = i >> 6;
            int gk = k0 + kk, gn = n0 + nn;
            float v = 0.f;
            if (gk < Kd && gn < N) v = Bm[(long long)gk * ldb + gn];
            Bs[kk][nn] = v;
        }
        __syncthreads();
#pragma unroll
        for (int kk = 0; kk < 16; kk++) {
            float4 av = *(const float4*)&As[kk][ty * 4];
            float4 bv = *(const float4*)&Bs[kk][tx * 4];
            float a4[4] = {av.x, av.y, av.z, av.w};
            float b4[4] = {bv.x, bv.y, bv.z, bv.w};
#pragma unroll
            for (int i = 0; i < 4; i++)
#pragma unroll
                for (int j = 0; j < 4; j++)
                    acc[i][j] = fmaf(a4[i], b4[j], acc[i][j]);
        }
        __syncthreads();
    }

    const float* xxb = (mode == 4) ? vrow + (long long)blockIdx.z * M : nullptr;
#pragma unroll
    for (int i = 0; i < 4; i++) {
        int m = m0 + ty * 4 + i;
        if (m >= M) continue;
#pragma unroll
        for (int j = 0; j < 4; j++) {
            int n = n0 + tx * 4 + j;
            if (n >= N) continue;
            float v = acc[i][j];
            if (mode == 1) {
                v = vrow[m] * (v * BN_INVF) + vrow[M + m];
                v = v > 0.f ? v : 0.2f * v;
            } else if (mode == 4) {
                v = 2.f * v - xxb[m] - xxb[n];
            }
            Cm[(long long)m * ldc + n] = v;
        }
    }
}

// Skinny GEMM for the transformer: A (2 x 65 x K) @ B (K x N) with split-K.
// grid = (N/64, S, 2); each block computes a 65x64 partial over K/S and writes
// P[((b*S+s)*65 + m)*N + n].
__launch_bounds__(256)
__global__ void skinny_gemm_kernel(const float* __restrict__ A, const float* __restrict__ B,
                                   float* __restrict__ P, int N, int K, int lda,
                                   long long sA, int S) {
    const int M = 65;
    int tid = threadIdx.x, tx = tid & 15, ty = tid >> 4;
    int n0 = blockIdx.x * 64;
    int s = blockIdx.y, b = blockIdx.z;
    int kchunk = K / S;
    int k0 = s * kchunk;
    A += (long long)b * sA;
    float* Pb = P + (((long long)b * S + s) * M) * N;

    __shared__ float As[16][81];   // 81: conflict-free staging writes
    __shared__ float Bs[16][64];
    float acc[5][4] = {};

    for (int kc = k0; kc < k0 + kchunk; kc += 16) {
#pragma unroll
        for (int e = 0; e < 5; e++) {
            int i = tid + e * 256;       // covers 16 x 80
            int m = i >> 4, kk = i & 15;
            As[kk][m] = (m < M) ? A[(long long)m * lda + kc + kk] : 0.f;
        }
#pragma unroll
        for (int e = 0; e < 4; e++) {
            int i = tid + e * 256;
            int kk = i >> 6, nn = i & 63;
            Bs[kk][nn] = B[(long long)(kc + kk) * N + n0 + nn];
        }
        __syncthreads();
#pragma unroll
        for (int kk = 0; kk < 16; kk++) {
            float4 bv = *(const float4*)&Bs[kk][tx * 4];
            float b4[4] = {bv.x, bv.y, bv.z, bv.w};
#pragma unroll
            for (int r = 0; r < 5; r++) {
                float a = As[kk][ty + r * 16];
#pragma unroll
                for (int c = 0; c < 4; c++) acc[r][c] = fmaf(a, b4[c], acc[r][c]);
            }
        }
        __syncthreads();
    }
#pragma unroll
    for (int r = 0; r < 5; r++) {
        int m = ty + r * 16;
        if (m < M) {
            float4 v = make_float4(acc[r][0], acc[r][1], acc[r][2], acc[r][3]);
            *(float4*)&Pb[(long long)m * N + n0 + (tx << 2)] = v;
        }
    }
}

// reduce partials over S + epilogue.
// mode 0: C = sum; mode 1: C += sum + bias[n]; mode 2: C = gelu(sum + bias[n])
__global__ void reduce_epi_kernel(const float* __restrict__ P, float* __restrict__ C,
                                  const float* __restrict__ bias,
                                  int N, int S, int mode) {
    const int M = 65;
    int i = blockIdx.x * blockDim.x + threadIdx.x;
    int total = 2 * M * N;
    if (i >= total) return;
    int b = i / (M * N), r = i % (M * N);
    int m = r / N, n = r % N;
    const float* p = P + (((long long)b * S) * M + m) * N + n;
    long long stride = (long long)M * N;
    float s = 0.f;
    for (int ss = 0; ss < S; ss++) s += p[ss * stride];
    long long co = ((long long)b * M + m) * N + n;
    if (mode == 0) {
        C[co] = s;
    } else if (mode == 1) {
        C[co] += s + bias[n];
    } else {
        float v = s + bias[n];
        C[co] = 0.5f * v * (1.f + erff(v * 0.70710678118654752f));
    }
}

// top-20 (largest, lower-index tie-break) per row of pd (4096 rows x 2048)
__global__ void topk_kernel(const float* __restrict__ pd, int* __restrict__ idxo) {
    int row = blockIdx.x;
    const float* p = pd + (long long)row * 2048;
    int tid = threadIdx.x;
    float vals[8];
#pragma unroll
    for (int j = 0; j < 8; j++) vals[j] = p[tid + j * 256];
    __shared__ unsigned long long sred[4];
    __shared__ int swin;
    int* out = idxo + (long long)row * 20;
    for (int k = 0; k < 20; k++) {
        float bv = vals[0]; int bj = 0;
#pragma unroll
        for (int j = 1; j < 8; j++) if (vals[j] > bv) { bv = vals[j]; bj = j; }
        int m = tid + bj * 256;
        unsigned long long pk = ((unsigned long long)fkey(bv) << 32) | (unsigned)(2048 - m);
        for (int off = 32; off; off >>= 1) {
            unsigned long long o2 = shfl_down_u64(pk, off);
            if (o2 > pk) pk = o2;
        }
        if ((tid & 63) == 0) sred[tid >> 6] = pk;
        __syncthreads();
        if (tid == 0) {
            unsigned long long best = sred[0];
            for (int w = 1; w < 4; w++) if (sred[w] > best) best = sred[w];
            int mwin = 2048 - (int)(best & 0xffffffffu);
            swin = mwin;
            out[k] = mwin;
        }
        __syncthreads();
        int mwin = swin;
        if ((mwin & 255) == tid) vals[mwin >> 8] = -3.0e38f;
        __syncthreads();
    }
}

// wcat (2O x C): rows 0..O-1 = w[:, :C]; rows O..2O-1 = w[:, C:] - w[:, :C]
__global__ void wcat_kernel(const float* __restrict__ w, float* __restrict__ wcat, int O, int C) {
    int i = blockIdx.x * blockDim.x + threadIdx.x;
    if (i >= 2 * O * C) return;
    int o2 = i / C, c = i % C;
    if (o2 < O) wcat[i] = w[o2 * 2 * C + c];
    else { int o = o2 - O; wcat[i] = w[o * 2 * C + C + c] - w[o * 2 * C + c]; }
}

// out[b,o,n] = max_k lrelu(bn( Y[b,o,idx[b,n,k]] + Y[b,O+o,n] ))
__global__ void gather_max_kernel(const float* __restrict__ Y, const int* __restrict__ idx,
                                  const float* __restrict__ bn, float* __restrict__ out, int O) {
    int i = blockIdx.x * blockDim.x + threadIdx.x;
    int total = 2 * O * 2048;
    if (i >= total) return;
    int b = i / (O * 2048), r = i % (O * 2048), o = r / 2048, n = r % 2048;
    const float* Arow = Y + ((long long)b * 2 * O + o) * 2048;
    float bc = Y[((long long)b * 2 * O + O + o) * 2048 + n];
    float sc = bn[o], sh = bn[O + o];
    const int* ip = idx + ((long long)b * 2048 + n) * 20;
    float best = -3.0e38f;
#pragma unroll
    for (int k = 0; k < 20; k++) {
        int m = ip[k];
        float y = Arow[m] + bc;
        float v = sc * (y * BN_INVF) + sh;
        v = v > 0.f ? v : 0.2f * v;
        best = fmaxf(best, v);
    }
    out[(long long)b * (512 * 2048) + (long long)o * 2048 + n] = best;
}

// h[b,1+p,o] = max over 32 points of y5[b,o,32p+i]
__global__ void pool_kernel(const float* __restrict__ y5, float* __restrict__ h) {
    int i = blockIdx.x * blockDim.x + threadIdx.x;
    if (i >= 2 * 64 * 1024) return;
    int b = i / (64 * 1024), r = i % (64 * 1024), p = r / 1024, o = r % 1024;
    const float* src = y5 + ((long long)b * 1024 + o) * 2048 + p * 32;
    float mx = src[0];
#pragma unroll
    for (int j = 1; j < 32; j++) mx = fmaxf(mx, src[j]);
    h[((long long)b * 65 + 1 + p) * 1024 + o] = mx;
}

__global__ void cls_kernel(const float* __restrict__ cls, float* __restrict__ h) {
    int i = blockIdx.x * blockDim.x + threadIdx.x;
    if (i >= 2 * 1024) return;
    int b = i / 1024, d = i % 1024;
    h[(long long)(b * 65) * 1024 + d] = cls[d];
}

__global__ void addpos_kernel(float* __restrict__ h, const float* __restrict__ pos) {
    int i = blockIdx.x * blockDim.x + threadIdx.x;
    if (i >= 2 * 65 * 1024) return;
    h[i] += pos[i];
}

// layernorm per row of 1024
__global__ void ln_kernel(const float* __restrict__ xin, const float* __restrict__ g,
                          const float* __restrict__ bta, float* __restrict__ out) {
    __shared__ float sbuf[4];
    int row = blockIdx.x;
    const float* x = xin + (long long)row * 1024;
    float* o = out + (long long)row * 1024;
    float loc[4];
    float s = 0.f;
#pragma unroll
    for (int i = 0; i < 4; i++) { loc[i] = x[threadIdx.x + i * 256]; s += loc[i]; }
    float mean = block_sum256(s, sbuf) * (1.f / 1024.f);
    float s2 = 0.f;
#pragma unroll
    for (int i = 0; i < 4; i++) { float d = loc[i] - mean; s2 = fmaf(d, d, s2); }
    float var = block_sum256(s2, sbuf) * (1.f / 1024.f);
    float inv = rsqrtf(var + LN_EPSF);
#pragma unroll
    for (int i = 0; i < 4; i++) {
        int d = threadIdx.x + i * 256;
        o[d] = (loc[i] - mean) * inv * g[d] + bta[d];
    }
}

// one block per (l, head, b); qkv (B,65,1536) packed [q|k|v] with head-major 64
__global__ void attn_kernel(const float* __restrict__ qkv, float* __restrict__ z) {
    int l = blockIdx.x, hh = blockIdx.y, b = blockIdx.z;
    __shared__ float qs[64];
    __shared__ float sc[65];
    __shared__ float sred[2];
    int tid = threadIdx.x;
    const float* base = qkv + (long long)b * 65 * 1536;
    if (tid < 64) qs[tid] = base[(long long)l * 1536 + hh * 64 + tid];
    __syncthreads();
    if (tid < 65) {
        const float* kp = base + (long long)tid * 1536 + 512 + hh * 64;
        float d = 0.f;
#pragma unroll
        for (int c = 0; c < 64; c++) d = fmaf(qs[c], kp[c], d);
        sc[tid] = d * 0.125f;
    }
    __syncthreads();
    if (tid == 0) { float mx = sc[0]; for (int i = 1; i < 65; i++) mx = fmaxf(mx, sc[i]); sred[0] = mx; }
    __syncthreads();
    if (tid < 65) sc[tid] = expf(sc[tid] - sred[0]);
    __syncthreads();
    if (tid == 0) { float sm = 0.f; for (int i = 0; i < 65; i++) sm += sc[i]; sred[1] = sm; }
    __syncthreads();
    if (tid < 65) sc[tid] = sc[tid] / sred[1];
    __syncthreads();
    if (tid < 64) {
        float a = 0.f;
        const float* vp = base + 1024 + hh * 64 + tid;
        for (int m = 0; m < 65; m++) a = fmaf(sc[m], vp[(long long)m * 1536], a);
        z[((long long)b * 65 + l) * 512 + hh * 64 + tid] = a;
    }
}

__global__ void outcopy_kernel(const float* __restrict__ h, float* __restrict__ out) {
    int i = blockIdx.x * blockDim.x + threadIdx.x;
    if (i >= 2 * 64 * 1024) return;
    int b = i / (64 * 1024), r = i % (64 * 1024);
    out[i] = h[((long long)b * 65 + 1) * 1024 + r];
}

// ---------------- host side ----------------

static void graph_layer(hipStream_t stream, const float* xin, long long xin_bstr, int C,
                        const float* w, const float* bn, int O,
                        float* xxb, float* pdb, int* idxb, float* wcatb, float* Yb,
                        float* outp) {
    xx_kernel<<<(2 * 2048 + 255) / 256, 256, 0, stream>>>(xin, xxb, C, xin_bstr);
    {
        dim3 g(2048 / 64, 2048 / 64, 2);
        gemm_kernel<<<g, 256, 0, stream>>>(xin, xin, pdb, xxb,
                                           2048, 2048, C, 2048, 2048, 2048,
                                           xin_bstr, xin_bstr, (long long)2048 * 2048,
                                           1, 4);
    }
    topk_kernel<<<2 * 2048, 256, 0, stream>>>(pdb, idxb);
    wcat_kernel<<<(2 * O * C + 255) / 256, 256, 0, stream>>>(w, wcatb, O, C);
    {
        dim3 g(2048 / 64, (2 * O + 63) / 64, 2);
        gemm_kernel<<<g, 256, 0, stream>>>(wcatb, xin, Yb, nullptr,
                                           2 * O, 2048, C, C, 2048, 2048,
                                           0, xin_bstr, (long long)2 * O * 2048,
                                           0, 0);
    }
    gather_max_kernel<<<(2 * O * 2048 + 255) / 256, 256, 0, stream>>>(Yb, idxb, bn, outp, O);
}

static void skinny(hipStream_t stream, const float* A, int lda, long long sA,
                   const float* B, int N, int K, int S,
                   float* P, float* C, const float* bias, int mode) {
    dim3 g(N / 64, S, 2);
    skinny_gemm_kernel<<<g, 256, 0, stream>>>(A, B, P, N, K, lda, sA, S);
    int total = 2 * 65 * N;
    reduce_epi_kernel<<<(total + 255) / 256, 256, 0, stream>>>(P, C, bias, N, S, mode);
}

extern "C" void kernel_launch(void* const* d_in, const int* in_sizes, int n_in,
                              void* d_out, int out_size, void* d_ws, size_t ws_size,
                              hipStream_t stream) {
    const float* x    = (const float*)d_in[0];
    const float* pos  = (const float*)d_in[1];
    const float* cls  = (const float*)d_in[2];
    const float* w1   = (const float*)d_in[3];
    const float* bn1  = (const float*)d_in[4];
    const float* w2   = (const float*)d_in[5];
    const float* bn2  = (const float*)d_in[6];
    const float* w3   = (const float*)d_in[7];
    const float* bn3  = (const float*)d_in[8];
    const float* w4   = (const float*)d_in[9];
    const float* bn4  = (const float*)d_in[10];
    const float* w5   = (const float*)d_in[11];
    const float* bn5  = (const float*)d_in[12];
    const float* ln1  = (const float*)d_in[13];
    const float* wqkv = (const float*)d_in[14];
    const float* wo   = (const float*)d_in[15];
    const float* bo   = (const float*)d_in[16];
    const float* ln2  = (const float*)d_in[17];
    const float* wf1  = (const float*)d_in[18];
    const float* bf1  = (const float*)d_in[19];
    const float* wf2  = (const float*)d_in[20];
    const float* bf2  = (const float*)d_in[21];
    float* outp = (float*)d_out;

    size_t off = 0;
    auto alloc = [&](size_t nbytes) {
        size_t p = off;
        off += (nbytes + 255) & ~(size_t)255;
        return p;
    };
    char* ws = (char*)d_ws;
    float* xT   = (float*)(ws + alloc((size_t)2 * 3 * 2048 * 4));
    float* xxb  = (float*)(ws + alloc((size_t)2 * 2048 * 4));
    int*   idxb = (int*)  (ws + alloc((size_t)2 * 2048 * 20 * 4));
    float* pdb  = (float*)(ws + alloc((size_t)2 * 2048 * 2048 * 4));   // reused as y5, then skinny partials
    float* wcatb= (float*)(ws + alloc((size_t)512 * 128 * 4));
    float* Yb   = (float*)(ws + alloc((size_t)2 * 512 * 2048 * 4));
    float* xcat = (float*)(ws + alloc((size_t)2 * 512 * 2048 * 4));
    float* hbuf = (float*)(ws + alloc((size_t)2 * 65 * 1024 * 4));
    float* tbuf = (float*)(ws + alloc((size_t)2 * 65 * 1024 * 4));
    float* qkvb = (float*)(ws + alloc((size_t)2 * 65 * 1536 * 4));
    float* zbuf = (float*)(ws + alloc((size_t)2 * 65 * 512 * 4));
    float* midb = (float*)(ws + alloc((size_t)2 * 65 * 2048 * 4));
    (void)ws_size; (void)in_sizes; (void)n_in; (void)out_size;

    // ---- DGCNN patch embed ----
    transpose_x_kernel<<<(2 * 3 * 2048 + 255) / 256, 256, 0, stream>>>(x, xT);

    long long cbs = (long long)512 * 2048;  // xcat batch stride
    graph_layer(stream, xT,                (long long)3 * 2048, 3,   w1, bn1, 64,  xxb, pdb, idxb, wcatb, Yb, xcat + 0);
    graph_layer(stream, xcat + 0,          cbs,                 64,  w2, bn2, 64,  xxb, pdb, idxb, wcatb, Yb, xcat + (long long)64 * 2048);
    graph_layer(stream, xcat + (long long)64 * 2048,  cbs,      64,  w3, bn3, 128, xxb, pdb, idxb, wcatb, Yb, xcat + (long long)128 * 2048);
    graph_layer(stream, xcat + (long long)128 * 2048, cbs,      128, w4, bn4, 256, xxb, pdb, idxb, wcatb, Yb, xcat + (long long)256 * 2048);

    // conv5: y5 = lrelu(bn5(w5 @ xcat)), y5 aliases pdb
    float* y5 = pdb;
    {
        dim3 g(2048 / 64, 1024 / 64, 2);
        gemm_kernel<<<g, 256, 0, stream>>>(w5, xcat, y5, bn5,
                                           1024, 2048, 512, 512, 2048, 2048,
                                           0, cbs, (long long)1024 * 2048, 0, 1);
    }
    pool_kernel<<<(2 * 64 * 1024 + 255) / 256, 256, 0, stream>>>(y5, hbuf);
    cls_kernel<<<(2 * 1024 + 255) / 256, 256, 0, stream>>>(cls, hbuf);

    // ---- transformer ----
    float* Pbuf = pdb;  // y5 consumed by pool; reuse as split-K partials (max 8.5 MB)
    for (int L = 0; L < 6; L++) {
        const float* ln1g = ln1 + (long long)L * 2048;
        const float* ln2g = ln2 + (long long)L * 2048;
        const float* wqkvL = wqkv + (long long)L * 1024 * 1536;
        const float* woL   = wo   + (long long)L * 512 * 1024;
        const float* boL   = bo   + (long long)L * 1024;
        const float* wf1L  = wf1  + (long long)L * 1024 * 2048;
        const float* bf1L  = bf1  + (long long)L * 2048;
        const float* wf2L  = wf2  + (long long)L * 2048 * 1024;
        const float* bf2L  = bf2  + (long long)L * 1024;

        addpos_kernel<<<(2 * 65 * 1024 + 255) / 256, 256, 0, stream>>>(hbuf, pos);
        ln_kernel<<<130, 256, 0, stream>>>(hbuf, ln1g, ln1g + 1024, tbuf);
        // qkv = t @ wqkv (no bias)
        skinny(stream, tbuf, 1024, (long long)65 * 1024, wqkvL, 1536, 1024, 8, Pbuf, qkvb, nullptr, 0);
        attn_kernel<<<dim3(65, 8, 2), 128, 0, stream>>>(qkvb, zbuf);
        // h += z @ wo + bo
        skinny(stream, zbuf, 512, (long long)65 * 512, woL, 1024, 512, 8, Pbuf, hbuf, boL, 1);
        ln_kernel<<<130, 256, 0, stream>>>(hbuf, ln2g, ln2g + 1024, tbuf);
        // mid = gelu(t @ wf1 + bf1)
        skinny(stream, tbuf, 1024, (long long)65 * 1024, wf1L, 2048, 1024, 8, Pbuf, midb, bf1L, 2);
        // h += mid @ wf2 + bf2
        skinny(stream, midb, 2048, (long long)65 * 2048, wf2L, 1024, 2048, 16, Pbuf, hbuf, bf2L, 1);
    }

    outcopy_kernel<<<(2 * 64 * 1024 + 255) / 256, 256, 0, stream>>>(hbuf, outp);
}

// Round 3
// 1369.599 us; speedup vs baseline: 3.9740x; 1.1364x over previous
//
#include <hip/hip_runtime.h>
#include <math.h>

#define BN_INVF 0.9999950000374998f
#define LN_EPSF 1e-5f

// ---------------- small helpers ----------------

__device__ inline float block_sum256(float v, float* sbuf) {
    for (int off = 32; off; off >>= 1) v += __shfl_down(v, off);
    int lane = threadIdx.x & 63, w = threadIdx.x >> 6;
    if (lane == 0) sbuf[w] = v;
    __syncthreads();
    float r;
    if (threadIdx.x == 0) { r = sbuf[0] + sbuf[1] + sbuf[2] + sbuf[3]; sbuf[0] = r; }
    __syncthreads();
    r = sbuf[0];
    __syncthreads();
    return r;
}

__device__ inline unsigned fkey(float v) {
    unsigned u = __float_as_uint(v);
    return (u & 0x80000000u) ? ~u : (u | 0x80000000u);
}

// ---------------- kernels ----------------

// x (2,2048,3) -> xT (2,3,2048)
__global__ void transpose_x_kernel(const float* __restrict__ x, float* __restrict__ xT) {
    int i = blockIdx.x * blockDim.x + threadIdx.x;
    if (i >= 2 * 3 * 2048) return;
    int b = i / (3 * 2048), r = i % (3 * 2048), c = r / 2048, n = r % 2048;
    xT[i] = x[(b * 2048 + n) * 3 + c];
}

// xx[b,n] = sum_c x[b,c,n]^2
__global__ void xx_kernel(const float* __restrict__ x, float* __restrict__ xx, int C, long long bstr) {
    int i = blockIdx.x * blockDim.x + threadIdx.x;
    if (i >= 2 * 2048) return;
    int b = i / 2048, n = i % 2048;
    const float* p = x + (long long)b * bstr + n;
    float s = 0.f;
    for (int c = 0; c < C; c++) { float v = p[(long long)c * 2048]; s = fmaf(v, v, s); }
    xx[i] = s;
}

// Generic tiled SGEMM: C = A @ B, 64x64 tile. As padded to 68 (2-way banks only).
// modes: 0 plain | 1 lrelu(bn) | 4: 2*acc - xx[m] - xx[n]
__launch_bounds__(256)
__global__ void gemm_kernel(const float* __restrict__ A, const float* __restrict__ Bm,
                            float* __restrict__ Cm,
                            const float* __restrict__ vrow,
                            int M, int N, int Kd, int lda, int ldb, int ldc,
                            long long sA, long long sB, long long sC,
                            int transA, int mode) {
    int tid = threadIdx.x;
    int tx = tid & 15, ty = tid >> 4;
    int m0 = blockIdx.y * 64, n0 = blockIdx.x * 64;
    A  += (long long)blockIdx.z * sA;
    Bm += (long long)blockIdx.z * sB;
    Cm += (long long)blockIdx.z * sC;

    __shared__ float As[16][68];
    __shared__ float Bs[16][64];
    float acc[4][4] = {};
    const bool vec = ((Kd & 15) == 0);   // uniform per dispatch

    for (int k0 = 0; k0 < Kd; k0 += 16) {
        if (vec) {
            if (transA) {
                int kk = tid >> 4, mq = tid & 15;
                float4 f = *(const float4*)&A[(long long)(k0 + kk) * lda + m0 + mq * 4];
                *(float4*)&As[kk][mq * 4] = f;
            } else {
                int mm = tid >> 2, kq = tid & 3;
                float4 f = *(const float4*)&A[(long long)(m0 + mm) * lda + k0 + kq * 4];
                As[kq * 4 + 0][mm] = f.x;
                As[kq * 4 + 1][mm] = f.y;
                As[kq * 4 + 2][mm] = f.z;
                As[kq * 4 + 3][mm] = f.w;
            }
            int kk = tid >> 4, nq = tid & 15;
            float4 g = *(const float4*)&Bm[(long long)(k0 + kk) * ldb + n0 + nq * 4];
            *(float4*)&Bs[kk][nq * 4] = g;
        } else {
#pragma unroll
            for (int e = 0; e < 4; e++) {
                int i = tid + e * 256;
                int kk, mm;
                if (transA) { mm = i & 63; kk = i >> 6; } else { kk = i & 15; mm = i >> 4; }
                int gm = m0 + mm, gk = k0 + kk;
                float v = 0.f;
                if (gm < M && gk < Kd)
                    v = transA ? A[(long long)gk * lda + gm] : A[(long long)gm * lda + gk];
                As[kk][mm] = v;
            }
#pragma unroll
            for (int e = 0; e < 4; e++) {
                int i = tid + e * 256;
                int nn = i & 63, kk = i >> 6;
                int gk = k0 + kk, gn = n0 + nn;
                float v = 0.f;
                if (gk < Kd && gn < N) v = Bm[(long long)gk * ldb + gn];
                Bs[kk][nn] = v;
            }
        }
        __syncthreads();
#pragma unroll
        for (int kk = 0; kk < 16; kk++) {
            float4 av = *(const float4*)&As[kk][ty * 4];
            float4 bv = *(const float4*)&Bs[kk][tx * 4];
            float a4[4] = {av.x, av.y, av.z, av.w};
            float b4[4] = {bv.x, bv.y, bv.z, bv.w};
#pragma unroll
            for (int i = 0; i < 4; i++)
#pragma unroll
                for (int j = 0; j < 4; j++)
                    acc[i][j] = fmaf(a4[i], b4[j], acc[i][j]);
        }
        __syncthreads();
    }

    const float* xxb = (mode == 4) ? vrow + (long long)blockIdx.z * M : nullptr;
#pragma unroll
    for (int i = 0; i < 4; i++) {
        int m = m0 + ty * 4 + i;
        if (m >= M) continue;
#pragma unroll
        for (int j = 0; j < 4; j++) {
            int n = n0 + tx * 4 + j;
            if (n >= N) continue;
            float v = acc[i][j];
            if (mode == 1) {
                v = vrow[m] * (v * BN_INVF) + vrow[M + m];
                v = v > 0.f ? v : 0.2f * v;
            } else if (mode == 4) {
                v = 2.f * v - xxb[m] - xxb[n];
            }
            Cm[(long long)m * ldc + n] = v;
        }
    }
}

// Skinny GEMM: A (130 x K contiguous) @ B (K x N) with split-K, both batches in one block.
// grid = (N/64, S); partial P[(s*130 + m)*N + n].
#define SK_M 130
#define SK_SLOTS 144
#define SK_PAD 145
__launch_bounds__(256)
__global__ void skinny_gemm_kernel(const float* __restrict__ A, const float* __restrict__ B,
                                   float* __restrict__ P, int N, int K, int lda, int S) {
    int tid = threadIdx.x, tx = tid & 15, ty = tid >> 4;
    int n0 = blockIdx.x * 64;
    int s = blockIdx.y;
    int kchunk = K / S;
    int k0 = s * kchunk;
    float* Pb = P + ((long long)s * SK_M) * N;

    __shared__ float As[16][SK_PAD];
    __shared__ float Bs[16][64];
    float acc[9][4] = {};

    for (int kc = k0; kc < k0 + kchunk; kc += 16) {
#pragma unroll
        for (int e = 0; e < 3; e++) {
            int idx = tid + e * 256;
            if (idx < SK_SLOTS * 4) {
                int m = idx >> 2, kq = idx & 3;
                float4 f = make_float4(0.f, 0.f, 0.f, 0.f);
                if (m < SK_M) f = *(const float4*)&A[(long long)m * lda + kc + kq * 4];
                As[kq * 4 + 0][m] = f.x;
                As[kq * 4 + 1][m] = f.y;
                As[kq * 4 + 2][m] = f.z;
                As[kq * 4 + 3][m] = f.w;
            }
        }
        {
            int kk = tid >> 4, nq = tid & 15;
            float4 g = *(const float4*)&B[(long long)(kc + kk) * N + n0 + nq * 4];
            *(float4*)&Bs[kk][nq * 4] = g;
        }
        __syncthreads();
#pragma unroll
        for (int kk = 0; kk < 16; kk++) {
            float4 bv = *(const float4*)&Bs[kk][tx * 4];
            float b4[4] = {bv.x, bv.y, bv.z, bv.w};
#pragma unroll
            for (int r = 0; r < 9; r++) {
                float a = As[kk][ty + r * 16];
#pragma unroll
                for (int c = 0; c < 4; c++) acc[r][c] = fmaf(a, b4[c], acc[r][c]);
            }
        }
        __syncthreads();
    }
#pragma unroll
    for (int r = 0; r < 9; r++) {
        int m = ty + r * 16;
        if (m < SK_M) {
            float4 v = make_float4(acc[r][0], acc[r][1], acc[r][2], acc[r][3]);
            *(float4*)&Pb[(long long)m * N + n0 + (tx << 2)] = v;
        }
    }
}

// reduce partials over S + epilogue. mode 0: C=sum; 1: C += sum+bias[n]; 2: C=gelu(sum+bias[n])
__global__ void reduce_epi_kernel(const float* __restrict__ P, float* __restrict__ C,
                                  const float* __restrict__ bias,
                                  int N, int S, int mode) {
    int i = blockIdx.x * blockDim.x + threadIdx.x;
    int total = SK_M * N;
    if (i >= total) return;
    int n = i % N;
    const float* p = P + i;
    long long stride = (long long)SK_M * N;
    float s = 0.f;
    for (int ss = 0; ss < S; ss++) s += p[ss * stride];
    if (mode == 0) {
        C[i] = s;
    } else if (mode == 1) {
        C[i] += s + bias[n];
    } else {
        float v = s + bias[n];
        C[i] = 0.5f * v * (1.f + erff(v * 0.70710678118654752f));
    }
}

// exact top-20 set per row of pd via 48-bit-key radix select (6-bit digits).
// key = fkey(v)<<16 | (2047-m)<<5  -> jax tie-break (lower index wins) exact.
__global__ void topk_kernel(const float* __restrict__ pd, int* __restrict__ idxo) {
    int row = blockIdx.x;
    const float* p = pd + (long long)row * 2048;
    int tid = threadIdx.x;
    int wid = tid >> 6, lane = tid & 63;
    unsigned long long key[8];
#pragma unroll
    for (int j = 0; j < 8; j++) {
        int m = tid + j * 256;
        key[j] = ((unsigned long long)fkey(p[m]) << 16) | (unsigned)((2047 - m) << 5);
    }
    __shared__ int hist[4][64];
    __shared__ unsigned long long sP;
    __shared__ int sdone, sneed, scount;
    if (tid == 0) { sneed = 20; scount = 0; }
    unsigned long long prefix = 0;
    int need = 20;
    int shift = 42;
    int donef = 0;
    unsigned long long Pfin = 0;
    int sfin = 0;
    for (int pass = 0; pass < 8 && !donef; pass++) {
        hist[wid][lane] = 0;
        __syncthreads();
#pragma unroll
        for (int j = 0; j < 8; j++) {
            if ((key[j] >> (shift + 6)) == prefix)
                atomicAdd(&hist[wid][(int)((key[j] >> shift) & 63)], 1);
        }
        __syncthreads();
        if (wid == 0) {
            int c = hist[0][lane] + hist[1][lane] + hist[2][lane] + hist[3][lane];
            int cnt = c;
            for (int off = 1; off < 64; off <<= 1) {
                int t = __shfl_down(cnt, off);
                if (lane + off < 64) cnt += t;
            }
            int above = __shfl_down(cnt, 1);
            if (lane == 63) above = 0;
            if (cnt >= need && above < need) {
                int nn = need - above;
                sP = (prefix << 6) | (unsigned long long)lane;
                if (c == nn || shift == 0) sdone = 1;
                else { sdone = 0; sneed = nn; }
            }
        }
        __syncthreads();
        donef = sdone;
        prefix = sP;
        need = sneed;
        if (donef) { Pfin = sP; sfin = shift; }
        shift -= 6;
        __syncthreads();
    }
    int* out = idxo + (long long)row * 20;
#pragma unroll
    for (int j = 0; j < 8; j++) {
        if ((key[j] >> sfin) >= Pfin) {
            int pos = atomicAdd(&scount, 1);
            if (pos < 20) out[pos] = tid + j * 256;
        }
    }
}

// wcat (2O x C)
__global__ void wcat_kernel(const float* __restrict__ w, float* __restrict__ wcat, int O, int C) {
    int i = blockIdx.x * blockDim.x + threadIdx.x;
    if (i >= 2 * O * C) return;
    int o2 = i / C, c = i % C;
    if (o2 < O) wcat[i] = w[o2 * 2 * C + c];
    else { int o = o2 - O; wcat[i] = w[o * 2 * C + C + c] - w[o * 2 * C + c]; }
}

// out[b,o,n] = max_k lrelu(bn( Y[b,o,idx[b,n,k]] + Y[b,O+o,n] ))
__global__ void gather_max_kernel(const float* __restrict__ Y, const int* __restrict__ idx,
                                  const float* __restrict__ bn, float* __restrict__ out, int O) {
    int i = blockIdx.x * blockDim.x + threadIdx.x;
    int total = 2 * O * 2048;
    if (i >= total) return;
    int b = i / (O * 2048), r = i % (O * 2048), o = r / 2048, n = r % 2048;
    const float* Arow = Y + ((long long)b * 2 * O + o) * 2048;
    float bc = Y[((long long)b * 2 * O + O + o) * 2048 + n];
    float sc = bn[o], sh = bn[O + o];
    const int* ip = idx + ((long long)b * 2048 + n) * 20;
    float best = -3.0e38f;
#pragma unroll
    for (int k = 0; k < 20; k++) {
        int m = ip[k];
        float y = Arow[m] + bc;
        float v = sc * (y * BN_INVF) + sh;
        v = v > 0.f ? v : 0.2f * v;
        best = fmaxf(best, v);
    }
    out[(long long)b * (512 * 2048) + (long long)o * 2048 + n] = best;
}

__global__ void pool_kernel(const float* __restrict__ y5, float* __restrict__ h) {
    int i = blockIdx.x * blockDim.x + threadIdx.x;
    if (i >= 2 * 64 * 1024) return;
    int b = i / (64 * 1024), r = i % (64 * 1024), p = r / 1024, o = r % 1024;
    const float* src = y5 + ((long long)b * 1024 + o) * 2048 + p * 32;
    float mx = src[0];
#pragma unroll
    for (int j = 1; j < 32; j++) mx = fmaxf(mx, src[j]);
    h[((long long)b * 65 + 1 + p) * 1024 + o] = mx;
}

__global__ void cls_kernel(const float* __restrict__ cls, float* __restrict__ h) {
    int i = blockIdx.x * blockDim.x + threadIdx.x;
    if (i >= 2 * 1024) return;
    int b = i / 1024, d = i % 1024;
    h[(long long)(b * 65) * 1024 + d] = cls[d];
}

// layernorm per row of 1024; optionally fuse h += pos (writes h back)
__global__ void ln_kernel(float* __restrict__ h, const float* __restrict__ pos,
                          const float* __restrict__ g, const float* __restrict__ bta,
                          float* __restrict__ out, int addpos) {
    __shared__ float sbuf[4];
    int row = blockIdx.x;
    float* x = h + (long long)row * 1024;
    float* o = out + (long long)row * 1024;
    float loc[4];
    float s = 0.f;
#pragma unroll
    for (int i = 0; i < 4; i++) {
        int d = threadIdx.x + i * 256;
        float v = x[d];
        if (addpos) { v += pos[(long long)row * 1024 + d]; x[d] = v; }
        loc[i] = v; s += v;
    }
    float mean = block_sum256(s, sbuf) * (1.f / 1024.f);
    float s2 = 0.f;
#pragma unroll
    for (int i = 0; i < 4; i++) { float d = loc[i] - mean; s2 = fmaf(d, d, s2); }
    float var = block_sum256(s2, sbuf) * (1.f / 1024.f);
    float inv = rsqrtf(var + LN_EPSF);
#pragma unroll
    for (int i = 0; i < 4; i++) {
        int d = threadIdx.x + i * 256;
        o[d] = (loc[i] - mean) * inv * g[d] + bta[d];
    }
}

// one block per (l, head, b)
__global__ void attn_kernel(const float* __restrict__ qkv, float* __restrict__ z) {
    int l = blockIdx.x, hh = blockIdx.y, b = blockIdx.z;
    __shared__ float qs[64];
    __shared__ float sc[65];
    __shared__ float sred[2];
    int tid = threadIdx.x;
    const float* base = qkv + (long long)b * 65 * 1536;
    if (tid < 64) qs[tid] = base[(long long)l * 1536 + hh * 64 + tid];
    __syncthreads();
    if (tid < 65) {
        const float* kp = base + (long long)tid * 1536 + 512 + hh * 64;
        float d = 0.f;
#pragma unroll
        for (int c = 0; c < 64; c++) d = fmaf(qs[c], kp[c], d);
        sc[tid] = d * 0.125f;
    }
    __syncthreads();
    if (tid == 0) { float mx = sc[0]; for (int i = 1; i < 65; i++) mx = fmaxf(mx, sc[i]); sred[0] = mx; }
    __syncthreads();
    if (tid < 65) sc[tid] = expf(sc[tid] - sred[0]);
    __syncthreads();
    if (tid == 0) { float sm = 0.f; for (int i = 0; i < 65; i++) sm += sc[i]; sred[1] = sm; }
    __syncthreads();
    if (tid < 65) sc[tid] = sc[tid] / sred[1];
    __syncthreads();
    if (tid < 64) {
        float a = 0.f;
        const float* vp = base + 1024 + hh * 64 + tid;
        for (int m = 0; m < 65; m++) a = fmaf(sc[m], vp[(long long)m * 1536], a);
        z[((long long)b * 65 + l) * 512 + hh * 64 + tid] = a;
    }
}

__global__ void outcopy_kernel(const float* __restrict__ h, float* __restrict__ out) {
    int i = blockIdx.x * blockDim.x + threadIdx.x;
    if (i >= 2 * 64 * 1024) return;
    int b = i / (64 * 1024), r = i % (64 * 1024);
    out[i] = h[((long long)b * 65 + 1) * 1024 + r];
}

// ---------------- host side ----------------

static void graph_layer(hipStream_t stream, const float* xin, long long xin_bstr, int C,
                        const float* w, const float* bn, int O,
                        float* xxb, float* pdb, int* idxb, float* wcatb, float* Yb,
                        float* outp) {
    xx_kernel<<<(2 * 2048 + 255) / 256, 256, 0, stream>>>(xin, xxb, C, xin_bstr);
    {
        dim3 g(2048 / 64, 2048 / 64, 2);
        gemm_kernel<<<g, 256, 0, stream>>>(xin, xin, pdb, xxb,
                                           2048, 2048, C, 2048, 2048, 2048,
                                           xin_bstr, xin_bstr, (long long)2048 * 2048,
                                           1, 4);
    }
    topk_kernel<<<2 * 2048, 256, 0, stream>>>(pdb, idxb);
    wcat_kernel<<<(2 * O * C + 255) / 256, 256, 0, stream>>>(w, wcatb, O, C);
    {
        dim3 g(2048 / 64, (2 * O + 63) / 64, 2);
        gemm_kernel<<<g, 256, 0, stream>>>(wcatb, xin, Yb, nullptr,
                                           2 * O, 2048, C, C, 2048, 2048,
                                           0, xin_bstr, (long long)2 * O * 2048,
                                           0, 0);
    }
    gather_max_kernel<<<(2 * O * 2048 + 255) / 256, 256, 0, stream>>>(Yb, idxb, bn, outp, O);
}

static void skinny(hipStream_t stream, const float* A, int lda,
                   const float* B, int N, int K, int S,
                   float* P, float* C, const float* bias, int mode) {
    dim3 g(N / 64, S);
    skinny_gemm_kernel<<<g, 256, 0, stream>>>(A, B, P, N, K, lda, S);
    int total = SK_M * N;
    reduce_epi_kernel<<<(total + 255) / 256, 256, 0, stream>>>(P, C, bias, N, S, mode);
}

extern "C" void kernel_launch(void* const* d_in, const int* in_sizes, int n_in,
                              void* d_out, int out_size, void* d_ws, size_t ws_size,
                              hipStream_t stream) {
    const float* x    = (const float*)d_in[0];
    const float* pos  = (const float*)d_in[1];
    const float* cls  = (const float*)d_in[2];
    const float* w1   = (const float*)d_in[3];
    const float* bn1  = (const float*)d_in[4];
    const float* w2   = (const float*)d_in[5];
    const float* bn2  = (const float*)d_in[6];
    const float* w3   = (const float*)d_in[7];
    const float* bn3  = (const float*)d_in[8];
    const float* w4   = (const float*)d_in[9];
    const float* bn4  = (const float*)d_in[10];
    const float* w5   = (const float*)d_in[11];
    const float* bn5  = (const float*)d_in[12];
    const float* ln1  = (const float*)d_in[13];
    const float* wqkv = (const float*)d_in[14];
    const float* wo   = (const float*)d_in[15];
    const float* bo   = (const float*)d_in[16];
    const float* ln2  = (const float*)d_in[17];
    const float* wf1  = (const float*)d_in[18];
    const float* bf1  = (const float*)d_in[19];
    const float* wf2  = (const float*)d_in[20];
    const float* bf2  = (const float*)d_in[21];
    float* outp = (float*)d_out;

    size_t off = 0;
    auto alloc = [&](size_t nbytes) {
        size_t p = off;
        off += (nbytes + 255) & ~(size_t)255;
        return p;
    };
    char* ws = (char*)d_ws;
    float* xT   = (float*)(ws + alloc((size_t)2 * 3 * 2048 * 4));
    float* xxb  = (float*)(ws + alloc((size_t)2 * 2048 * 4));
    int*   idxb = (int*)  (ws + alloc((size_t)2 * 2048 * 20 * 4));
    float* pdb  = (float*)(ws + alloc((size_t)2 * 2048 * 2048 * 4));   // reused: y5, then split-K partials
    float* wcatb= (float*)(ws + alloc((size_t)512 * 128 * 4));
    float* Yb   = (float*)(ws + alloc((size_t)2 * 512 * 2048 * 4));
    float* xcat = (float*)(ws + alloc((size_t)2 * 512 * 2048 * 4));
    float* hbuf = (float*)(ws + alloc((size_t)2 * 65 * 1024 * 4));
    float* tbuf = (float*)(ws + alloc((size_t)2 * 65 * 1024 * 4));
    float* qkvb = (float*)(ws + alloc((size_t)2 * 65 * 1536 * 4));
    float* zbuf = (float*)(ws + alloc((size_t)2 * 65 * 512 * 4));
    float* midb = (float*)(ws + alloc((size_t)2 * 65 * 2048 * 4));
    (void)ws_size; (void)in_sizes; (void)n_in; (void)out_size;

    // ---- DGCNN patch embed ----
    transpose_x_kernel<<<(2 * 3 * 2048 + 255) / 256, 256, 0, stream>>>(x, xT);

    long long cbs = (long long)512 * 2048;
    graph_layer(stream, xT,                (long long)3 * 2048, 3,   w1, bn1, 64,  xxb, pdb, idxb, wcatb, Yb, xcat + 0);
    graph_layer(stream, xcat + 0,          cbs,                 64,  w2, bn2, 64,  xxb, pdb, idxb, wcatb, Yb, xcat + (long long)64 * 2048);
    graph_layer(stream, xcat + (long long)64 * 2048,  cbs,      64,  w3, bn3, 128, xxb, pdb, idxb, wcatb, Yb, xcat + (long long)128 * 2048);
    graph_layer(stream, xcat + (long long)128 * 2048, cbs,      128, w4, bn4, 256, xxb, pdb, idxb, wcatb, Yb, xcat + (long long)256 * 2048);

    // conv5
    float* y5 = pdb;
    {
        dim3 g(2048 / 64, 1024 / 64, 2);
        gemm_kernel<<<g, 256, 0, stream>>>(w5, xcat, y5, bn5,
                                           1024, 2048, 512, 512, 2048, 2048,
                                           0, cbs, (long long)1024 * 2048, 0, 1);
    }
    pool_kernel<<<(2 * 64 * 1024 + 255) / 256, 256, 0, stream>>>(y5, hbuf);
    cls_kernel<<<(2 * 1024 + 255) / 256, 256, 0, stream>>>(cls, hbuf);

    // ---- transformer ----
    float* Pbuf = pdb;
    for (int L = 0; L < 6; L++) {
        const float* ln1g = ln1 + (long long)L * 2048;
        const float* ln2g = ln2 + (long long)L * 2048;
        const float* wqkvL = wqkv + (long long)L * 1024 * 1536;
        const float* woL   = wo   + (long long)L * 512 * 1024;
        const float* boL   = bo   + (long long)L * 1024;
        const float* wf1L  = wf1  + (long long)L * 1024 * 2048;
        const float* bf1L  = bf1  + (long long)L * 2048;
        const float* wf2L  = wf2  + (long long)L * 2048 * 1024;
        const float* bf2L  = bf2  + (long long)L * 1024;

        ln_kernel<<<130, 256, 0, stream>>>(hbuf, pos, ln1g, ln1g + 1024, tbuf, 1);
        skinny(stream, tbuf, 1024, wqkvL, 1536, 1024, 16, Pbuf, qkvb, nullptr, 0);
        attn_kernel<<<dim3(65, 8, 2), 128, 0, stream>>>(qkvb, zbuf);
        skinny(stream, zbuf, 512, woL, 1024, 512, 16, Pbuf, hbuf, boL, 1);
        ln_kernel<<<130, 256, 0, stream>>>(hbuf, nullptr, ln2g, ln2g + 1024, tbuf, 0);
        skinny(stream, tbuf, 1024, wf1L, 2048, 1024, 16, Pbuf, midb, bf1L, 2);
        skinny(stream, midb, 2048, wf2L, 1024, 2048, 32, Pbuf, hbuf, bf2L, 1);
    }

    outcopy_kernel<<<(2 * 64 * 1024 + 255) / 256, 256, 0, stream>>>(hbuf, outp);
}

// Round 4
// 1217.656 us; speedup vs baseline: 4.4699x; 1.1248x over previous
//
#include <hip/hip_runtime.h>
#include <hip/hip_bf16.h>
#include <math.h>

#define BN_INVF 0.9999950000374998f
#define LN_EPSF 1e-5f

typedef __attribute__((ext_vector_type(8))) short bf16x8;
typedef __attribute__((ext_vector_type(4))) float f32x4;

__device__ inline unsigned short f2bf(float v) {
    __hip_bfloat16 h = __float2bfloat16(v);
    return *(const unsigned short*)&h;
}

// ---------------- small helpers ----------------

__device__ inline float block_sum256(float v, float* sbuf) {
    for (int off = 32; off; off >>= 1) v += __shfl_down(v, off);
    int lane = threadIdx.x & 63, w = threadIdx.x >> 6;
    if (lane == 0) sbuf[w] = v;
    __syncthreads();
    float r;
    if (threadIdx.x == 0) { r = sbuf[0] + sbuf[1] + sbuf[2] + sbuf[3]; sbuf[0] = r; }
    __syncthreads();
    r = sbuf[0];
    __syncthreads();
    return r;
}

__device__ inline unsigned fkey(float v) {
    unsigned u = __float_as_uint(v);
    return (u & 0x80000000u) ? ~u : (u | 0x80000000u);
}

// ---------------- kernels ----------------

// xx[g] = sum_c x[g-row][c]^2, point-major rows; 4 lanes per row
__global__ void xx_kernel(const float* __restrict__ x, float* __restrict__ xx,
                          int C, int lda, long long bstr) {
    int g = blockIdx.x * 64 + (threadIdx.x >> 2);
    int q = threadIdx.x & 3;
    if (g >= 2 * 2048) return;
    int b = g >> 11, n = g & 2047;
    const float* p = x + (long long)b * bstr + (long long)n * lda;
    float s = 0.f;
    for (int c = q; c < C; c += 4) { float v = p[c]; s = fmaf(v, v, s); }
    s += __shfl_down(s, 1);
    s += __shfl_down(s, 2);
    if (q == 0) xx[g] = s;
}

// fp32 NT GEMM: C[m][n] = sum_k A[m][k]*B[n][k].  modes: 0 plain | 4: 2*acc-xx[m]-xx[n]
__launch_bounds__(256)
__global__ void gemm_nt_kernel(const float* __restrict__ A, const float* __restrict__ Bm,
                               float* __restrict__ Cm, const float* __restrict__ vrow,
                               int M, int N, int Kd, int lda, int ldb, int ldc,
                               long long sA, long long sB, long long sC, int mode) {
    int tid = threadIdx.x;
    int tx = tid & 15, ty = tid >> 4;
    int m0 = blockIdx.y * 64, n0 = blockIdx.x * 64;
    A  += (long long)blockIdx.z * sA;
    Bm += (long long)blockIdx.z * sB;
    Cm += (long long)blockIdx.z * sC;

    __shared__ float As[16][68];
    __shared__ float Bs[16][68];
    float acc[4][4] = {};
    const bool vec = ((Kd & 15) == 0);

    for (int k0 = 0; k0 < Kd; k0 += 16) {
        if (vec) {
            int row = tid >> 2, q = tid & 3;
            float4 f = *(const float4*)&A[(long long)(m0 + row) * lda + k0 + q * 4];
            As[q * 4 + 0][row] = f.x; As[q * 4 + 1][row] = f.y;
            As[q * 4 + 2][row] = f.z; As[q * 4 + 3][row] = f.w;
            float4 g = *(const float4*)&Bm[(long long)(n0 + row) * ldb + k0 + q * 4];
            Bs[q * 4 + 0][row] = g.x; Bs[q * 4 + 1][row] = g.y;
            Bs[q * 4 + 2][row] = g.z; Bs[q * 4 + 3][row] = g.w;
        } else {
#pragma unroll
            for (int e = 0; e < 4; e++) {
                int i = tid + e * 256;
                int kk = i & 15, mm = i >> 4;
                int gk = k0 + kk;
                As[kk][mm] = (gk < Kd) ? A[(long long)(m0 + mm) * lda + gk] : 0.f;
            }
#pragma unroll
            for (int e = 0; e < 4; e++) {
                int i = tid + e * 256;
                int kk = i & 15, nn = i >> 4;
                int gk = k0 + kk;
                Bs[kk][nn] = (gk < Kd) ? Bm[(long long)(n0 + nn) * ldb + gk] : 0.f;
            }
        }
        __syncthreads();
#pragma unroll
        for (int kk = 0; kk < 16; kk++) {
            float4 av = *(const float4*)&As[kk][ty * 4];
            float4 bv = *(const float4*)&Bs[kk][tx * 4];
            float a4[4] = {av.x, av.y, av.z, av.w};
            float b4[4] = {bv.x, bv.y, bv.z, bv.w};
#pragma unroll
            for (int i = 0; i < 4; i++)
#pragma unroll
                for (int j = 0; j < 4; j++)
                    acc[i][j] = fmaf(a4[i], b4[j], acc[i][j]);
        }
        __syncthreads();
    }

    const float* xxb = (mode == 4) ? vrow + (long long)blockIdx.z * M : nullptr;
#pragma unroll
    for (int i = 0; i < 4; i++) {
        int m = m0 + ty * 4 + i;
#pragma unroll
        for (int j = 0; j < 4; j++) {
            int n = n0 + tx * 4 + j;
            float v = acc[i][j];
            if (mode == 4) v = 2.f * v - xxb[m] - xxb[n];
            Cm[(long long)m * ldc + n] = v;
        }
    }
}

// bf16 MFMA NT GEMM: C[m][n] = sum_k A[m][k]*B[n][k]; 128x128 tile, bk=32.
// grid (Nr/128, Mr/128, batch); B unbatched. mode 0: plain; 1: lrelu(bn) with bn[col].
__launch_bounds__(256)
__global__ void mfma_nt_kernel(const unsigned short* __restrict__ A,
                               const unsigned short* __restrict__ Bv,
                               float* __restrict__ C, const float* __restrict__ bn,
                               int Nr, int K, int lda, int ldb, int ldc,
                               long long sA, long long sC, int mode) {
    int tid = threadIdx.x;
    int wave = tid >> 6, lane = tid & 63;
    int wm = (wave >> 1) * 64, wn = (wave & 1) * 64;
    int m0 = blockIdx.y * 128, n0 = blockIdx.x * 128;
    A += (long long)blockIdx.z * sA;
    C += (long long)blockIdx.z * sC;

    __shared__ __align__(16) unsigned short As[128 * 40];
    __shared__ __align__(16) unsigned short Bs[128 * 40];
    f32x4 acc[4][4];
#pragma unroll
    for (int i = 0; i < 4; i++)
#pragma unroll
        for (int j = 0; j < 4; j++) acc[i][j] = (f32x4){0.f, 0.f, 0.f, 0.f};

    int lr = lane & 15, lk = (lane >> 4) * 8;

    for (int k0 = 0; k0 < K; k0 += 32) {
#pragma unroll
        for (int e = 0; e < 2; e++) {
            int idx = tid + e * 256;
            int row = idx >> 2, q = idx & 3;
            float4 f = *(const float4*)&A[(long long)(m0 + row) * lda + k0 + q * 8];
            *(float4*)&As[row * 40 + q * 8] = f;
        }
#pragma unroll
        for (int e = 0; e < 2; e++) {
            int idx = tid + e * 256;
            int row = idx >> 2, q = idx & 3;
            float4 f = *(const float4*)&Bv[(long long)(n0 + row) * ldb + k0 + q * 8];
            *(float4*)&Bs[row * 40 + q * 8] = f;
        }
        __syncthreads();
        bf16x8 af[4], bf[4];
#pragma unroll
        for (int t = 0; t < 4; t++) af[t] = *(const bf16x8*)&As[(wm + t * 16 + lr) * 40 + lk];
#pragma unroll
        for (int t = 0; t < 4; t++) bf[t] = *(const bf16x8*)&Bs[(wn + t * 16 + lr) * 40 + lk];
#pragma unroll
        for (int i = 0; i < 4; i++)
#pragma unroll
            for (int j = 0; j < 4; j++)
                acc[i][j] = __builtin_amdgcn_mfma_f32_16x16x32_bf16(af[i], bf[j], acc[i][j], 0, 0, 0);
        __syncthreads();
    }

    int cr = (lane >> 4) << 2;
#pragma unroll
    for (int i = 0; i < 4; i++) {
        int rbase = m0 + wm + i * 16 + cr;
#pragma unroll
        for (int j = 0; j < 4; j++) {
            int col = n0 + wn + j * 16 + (lane & 15);
            float bsc = 0.f, bsh = 0.f;
            if (mode == 1) { bsc = bn[col]; bsh = bn[Nr + col]; }
#pragma unroll
            for (int r = 0; r < 4; r++) {
                float v = acc[i][j][r];
                if (mode == 1) {
                    v = bsc * (v * BN_INVF) + bsh;
                    v = v > 0.f ? v : 0.2f * v;
                }
                C[(long long)(rbase + r) * ldc + col] = v;
            }
        }
    }
}

// Skinny GEMM (transformer): A (130 x K) @ B (K x N), split-K.
#define SK_M 130
#define SK_SLOTS 144
#define SK_PAD 145
__launch_bounds__(256)
__global__ void skinny_gemm_kernel(const float* __restrict__ A, const float* __restrict__ B,
                                   float* __restrict__ P, int N, int K, int lda, int S) {
    int tid = threadIdx.x, tx = tid & 15, ty = tid >> 4;
    int n0 = blockIdx.x * 64;
    int s = blockIdx.y;
    int kchunk = K / S;
    int k0 = s * kchunk;
    float* Pb = P + ((long long)s * SK_M) * N;

    __shared__ float As[16][SK_PAD];
    __shared__ float Bs[16][64];
    float acc[9][4] = {};

    for (int kc = k0; kc < k0 + kchunk; kc += 16) {
#pragma unroll
        for (int e = 0; e < 3; e++) {
            int idx = tid + e * 256;
            if (idx < SK_SLOTS * 4) {
                int m = idx >> 2, kq = idx & 3;
                float4 f = make_float4(0.f, 0.f, 0.f, 0.f);
                if (m < SK_M) f = *(const float4*)&A[(long long)m * lda + kc + kq * 4];
                As[kq * 4 + 0][m] = f.x;
                As[kq * 4 + 1][m] = f.y;
                As[kq * 4 + 2][m] = f.z;
                As[kq * 4 + 3][m] = f.w;
            }
        }
        {
            int kk = tid >> 4, nq = tid & 15;
            float4 g = *(const float4*)&B[(long long)(kc + kk) * N + n0 + nq * 4];
            *(float4*)&Bs[kk][nq * 4] = g;
        }
        __syncthreads();
#pragma unroll
        for (int kk = 0; kk < 16; kk++) {
            float4 bv = *(const float4*)&Bs[kk][tx * 4];
            float b4[4] = {bv.x, bv.y, bv.z, bv.w};
#pragma unroll
            for (int r = 0; r < 9; r++) {
                float a = As[kk][ty + r * 16];
#pragma unroll
                for (int c = 0; c < 4; c++) acc[r][c] = fmaf(a, b4[c], acc[r][c]);
            }
        }
        __syncthreads();
    }
#pragma unroll
    for (int r = 0; r < 9; r++) {
        int m = ty + r * 16;
        if (m < SK_M) {
            float4 v = make_float4(acc[r][0], acc[r][1], acc[r][2], acc[r][3]);
            *(float4*)&Pb[(long long)m * N + n0 + (tx << 2)] = v;
        }
    }
}

// reduce partials + epilogue. mode 0: C=sum; 1: C += sum+bias[n]; 2: C=gelu(sum+bias[n])
__global__ void reduce_epi_kernel(const float* __restrict__ P, float* __restrict__ C,
                                  const float* __restrict__ bias, int N, int S, int mode) {
    int i = blockIdx.x * blockDim.x + threadIdx.x;
    int total = SK_M * N;
    if (i >= total) return;
    int n = i % N;
    const float* p = P + i;
    long long stride = (long long)SK_M * N;
    float s = 0.f;
    for (int ss = 0; ss < S; ss++) s += p[ss * stride];
    if (mode == 0) {
        C[i] = s;
    } else if (mode == 1) {
        C[i] += s + bias[n];
    } else {
        float v = s + bias[n];
        C[i] = 0.5f * v * (1.f + erff(v * 0.70710678118654752f));
    }
}

// exact top-20 per row of pd via 48-bit-key radix select
__global__ void topk_kernel(const float* __restrict__ pd, int* __restrict__ idxo) {
    int row = blockIdx.x;
    const float* p = pd + (long long)row * 2048;
    int tid = threadIdx.x;
    int wid = tid >> 6, lane = tid & 63;
    unsigned long long key[8];
#pragma unroll
    for (int j = 0; j < 8; j++) {
        int m = tid + j * 256;
        key[j] = ((unsigned long long)fkey(p[m]) << 16) | (unsigned)((2047 - m) << 5);
    }
    __shared__ int hist[4][64];
    __shared__ unsigned long long sP;
    __shared__ int sdone, sneed, scount;
    if (tid == 0) { sneed = 20; scount = 0; }
    unsigned long long prefix = 0;
    int need = 20;
    int shift = 42;
    int donef = 0;
    unsigned long long Pfin = 0;
    int sfin = 0;
    for (int pass = 0; pass < 8 && !donef; pass++) {
        hist[wid][lane] = 0;
        __syncthreads();
#pragma unroll
        for (int j = 0; j < 8; j++) {
            if ((key[j] >> (shift + 6)) == prefix)
                atomicAdd(&hist[wid][(int)((key[j] >> shift) & 63)], 1);
        }
        __syncthreads();
        if (wid == 0) {
            int c = hist[0][lane] + hist[1][lane] + hist[2][lane] + hist[3][lane];
            int cnt = c;
            for (int off = 1; off < 64; off <<= 1) {
                int t = __shfl_down(cnt, off);
                if (lane + off < 64) cnt += t;
            }
            int above = __shfl_down(cnt, 1);
            if (lane == 63) above = 0;
            if (cnt >= need && above < need) {
                int nn = need - above;
                sP = (prefix << 6) | (unsigned long long)lane;
                if (c == nn || shift == 0) sdone = 1;
                else { sdone = 0; sneed = nn; }
            }
        }
        __syncthreads();
        donef = sdone;
        prefix = sP;
        need = sneed;
        if (donef) { Pfin = sP; sfin = shift; }
        shift -= 6;
        __syncthreads();
    }
    int* out = idxo + (long long)row * 20;
#pragma unroll
    for (int j = 0; j < 8; j++) {
        if ((key[j] >> sfin) >= Pfin) {
            int pos = atomicAdd(&scount, 1);
            if (pos < 20) out[pos] = tid + j * 256;
        }
    }
}

// wcat (2O x C): rows 0..O-1 = w[:, :C]; rows O..2O-1 = w[:, C:] - w[:, :C]; emits f32 + bf16
__global__ void wcat_kernel(const float* __restrict__ w, float* __restrict__ wf,
                            unsigned short* __restrict__ wb, int O, int C) {
    int i = blockIdx.x * blockDim.x + threadIdx.x;
    if (i >= 2 * O * C) return;
    int o2 = i / C, c = i % C;
    float v;
    if (o2 < O) v = w[o2 * 2 * C + c];
    else { int o = o2 - O; v = w[o * 2 * C + C + c] - w[o * 2 * C + c]; }
    wf[i] = v;
    wb[i] = f2bf(v);
}

__global__ void cast_kernel(const float* __restrict__ a, unsigned short* __restrict__ o, int n) {
    int i = blockIdx.x * blockDim.x + threadIdx.x;
    if (i < n) o[i] = f2bf(a[i]);
}

// point-major gather+max: out[n][o] = max_k lrelu(bn_o(Y[idx[n,k]][o] + Y[n][O+o]))
// Y per-batch rows 2048 x (2O); outputs written into xcat slice (row stride 512), fp32+bf16
__global__ void gather_max_kernel(const float* __restrict__ Y, const int* __restrict__ idx,
                                  const float* __restrict__ bn,
                                  float* __restrict__ outF, unsigned short* __restrict__ outB,
                                  int O) {
    int i = blockIdx.x * blockDim.x + threadIdx.x;
    if (i >= 2 * 2048 * O) return;
    int o = i % O;
    int t = i / O;
    int n = t & 2047, b = t >> 11;
    const float* Yb = Y + (long long)b * 2048 * (2 * O);
    float center = Yb[(long long)n * (2 * O) + O + o];
    float sc = bn[o], sh = bn[O + o];
    const int* ip = idx + ((long long)b * 2048 + n) * 20;
    float best = -3.0e38f;
#pragma unroll
    for (int k = 0; k < 20; k++) {
        int m = ip[k];
        float y = Yb[(long long)m * (2 * O) + o] + center;
        float v = sc * (y * BN_INVF) + sh;
        v = v > 0.f ? v : 0.2f * v;
        best = fmaxf(best, v);
    }
    long long oo = ((long long)b * 2048 + n) * 512 + o;
    outF[oo] = best;
    outB[oo] = f2bf(best);
}

// h[b,1+p,o] = max over 32 rows of y5[(b*2048+p*32+j)][o]
__global__ void pool_kernel(const float* __restrict__ y5, float* __restrict__ h) {
    int i = blockIdx.x * blockDim.x + threadIdx.x;
    if (i >= 2 * 64 * 1024) return;
    int o = i % 1024;
    int t = i / 1024;
    int p = t & 63, b = t >> 6;
    const float* src = y5 + ((long long)b * 2048 + p * 32) * 1024 + o;
    float mx = src[0];
#pragma unroll
    for (int j = 1; j < 32; j++) mx = fmaxf(mx, src[(long long)j * 1024]);
    h[((long long)b * 65 + 1 + p) * 1024 + o] = mx;
}

__global__ void cls_kernel(const float* __restrict__ cls, float* __restrict__ h) {
    int i = blockIdx.x * blockDim.x + threadIdx.x;
    if (i >= 2 * 1024) return;
    int b = i / 1024, d = i % 1024;
    h[(long long)(b * 65) * 1024 + d] = cls[d];
}

// layernorm per row of 1024; optionally fuse h += pos
__global__ void ln_kernel(float* __restrict__ h, const float* __restrict__ pos,
                          const float* __restrict__ g, const float* __restrict__ bta,
                          float* __restrict__ out, int addpos) {
    __shared__ float sbuf[4];
    int row = blockIdx.x;
    float* x = h + (long long)row * 1024;
    float* o = out + (long long)row * 1024;
    float loc[4];
    float s = 0.f;
#pragma unroll
    for (int i = 0; i < 4; i++) {
        int d = threadIdx.x + i * 256;
        float v = x[d];
        if (addpos) { v += pos[(long long)row * 1024 + d]; x[d] = v; }
        loc[i] = v; s += v;
    }
    float mean = block_sum256(s, sbuf) * (1.f / 1024.f);
    float s2 = 0.f;
#pragma unroll
    for (int i = 0; i < 4; i++) { float d = loc[i] - mean; s2 = fmaf(d, d, s2); }
    float var = block_sum256(s2, sbuf) * (1.f / 1024.f);
    float inv = rsqrtf(var + LN_EPSF);
#pragma unroll
    for (int i = 0; i < 4; i++) {
        int d = threadIdx.x + i * 256;
        o[d] = (loc[i] - mean) * inv * g[d] + bta[d];
    }
}

// one block per (l, head, b)
__global__ void attn_kernel(const float* __restrict__ qkv, float* __restrict__ z) {
    int l = blockIdx.x, hh = blockIdx.y, b = blockIdx.z;
    __shared__ float qs[64];
    __shared__ float sc[65];
    __shared__ float sred[2];
    int tid = threadIdx.x;
    const float* base = qkv + (long long)b * 65 * 1536;
    if (tid < 64) qs[tid] = base[(long long)l * 1536 + hh * 64 + tid];
    __syncthreads();
    if (tid < 65) {
        const float* kp = base + (long long)tid * 1536 + 512 + hh * 64;
        float d = 0.f;
#pragma unroll
        for (int c = 0; c < 64; c++) d = fmaf(qs[c], kp[c], d);
        sc[tid] = d * 0.125f;
    }
    __syncthreads();
    if (tid == 0) { float mx = sc[0]; for (int i = 1; i < 65; i++) mx = fmaxf(mx, sc[i]); sred[0] = mx; }
    __syncthreads();
    if (tid < 65) sc[tid] = expf(sc[tid] - sred[0]);
    __syncthreads();
    if (tid == 0) { float sm = 0.f; for (int i = 0; i < 65; i++) sm += sc[i]; sred[1] = sm; }
    __syncthreads();
    if (tid < 65) sc[tid] = sc[tid] / sred[1];
    __syncthreads();
    if (tid < 64) {
        float a = 0.f;
        const float* vp = base + 1024 + hh * 64 + tid;
        for (int m = 0; m < 65; m++) a = fmaf(sc[m], vp[(long long)m * 1536], a);
        z[((long long)b * 65 + l) * 512 + hh * 64 + tid] = a;
    }
}

__global__ void outcopy_kernel(const float* __restrict__ h, float* __restrict__ out) {
    int i = blockIdx.x * blockDim.x + threadIdx.x;
    if (i >= 2 * 64 * 1024) return;
    int b = i / (64 * 1024), r = i % (64 * 1024);
    out[i] = h[((long long)b * 65 + 1) * 1024 + r];
}

// ---------------- host side ----------------

static void skinny(hipStream_t stream, const float* A, int lda,
                   const float* B, int N, int K, int S,
                   float* P, float* C, const float* bias, int mode) {
    dim3 g(N / 64, S);
    skinny_gemm_kernel<<<g, 256, 0, stream>>>(A, B, P, N, K, lda, S);
    int total = SK_M * N;
    reduce_epi_kernel<<<(total + 255) / 256, 256, 0, stream>>>(P, C, bias, N, S, mode);
}

extern "C" void kernel_launch(void* const* d_in, const int* in_sizes, int n_in,
                              void* d_out, int out_size, void* d_ws, size_t ws_size,
                              hipStream_t stream) {
    const float* x    = (const float*)d_in[0];
    const float* pos  = (const float*)d_in[1];
    const float* cls  = (const float*)d_in[2];
    const float* w1   = (const float*)d_in[3];
    const float* bn1  = (const float*)d_in[4];
    const float* w2   = (const float*)d_in[5];
    const float* bn2  = (const float*)d_in[6];
    const float* w3   = (const float*)d_in[7];
    const float* bn3  = (const float*)d_in[8];
    const float* w4   = (const float*)d_in[9];
    const float* bn4  = (const float*)d_in[10];
    const float* w5   = (const float*)d_in[11];
    const float* bn5  = (const float*)d_in[12];
    const float* ln1  = (const float*)d_in[13];
    const float* wqkv = (const float*)d_in[14];
    const float* wo   = (const float*)d_in[15];
    const float* bo   = (const float*)d_in[16];
    const float* ln2  = (const float*)d_in[17];
    const float* wf1  = (const float*)d_in[18];
    const float* bf1  = (const float*)d_in[19];
    const float* wf2  = (const float*)d_in[20];
    const float* bf2  = (const float*)d_in[21];
    float* outp = (float*)d_out;

    size_t off = 0;
    auto alloc = [&](size_t nbytes) {
        size_t p = off;
        off += (nbytes + 255) & ~(size_t)255;
        return p;
    };
    char* ws = (char*)d_ws;
    float*          xxb    = (float*)(ws + alloc((size_t)2 * 2048 * 4));
    int*            idxb   = (int*)  (ws + alloc((size_t)2 * 2048 * 20 * 4));
    float*          pdb    = (float*)(ws + alloc((size_t)2 * 2048 * 2048 * 4));  // pd -> y5 -> splitK partials
    float*          wcatF  = (float*)(ws + alloc((size_t)512 * 128 * 4));
    unsigned short* wcatB  = (unsigned short*)(ws + alloc((size_t)512 * 128 * 2));
    float*          Yb     = (float*)(ws + alloc((size_t)2 * 2048 * 512 * 4));
    float*          xcatF  = (float*)(ws + alloc((size_t)2 * 2048 * 512 * 4));   // point-major [b*2048+n][512]
    unsigned short* xcatB  = (unsigned short*)(ws + alloc((size_t)2 * 2048 * 512 * 2));
    unsigned short* w5B    = (unsigned short*)(ws + alloc((size_t)1024 * 512 * 2));
    float*          hbuf   = (float*)(ws + alloc((size_t)2 * 65 * 1024 * 4));
    float*          tbuf   = (float*)(ws + alloc((size_t)2 * 65 * 1024 * 4));
    float*          qkvb   = (float*)(ws + alloc((size_t)2 * 65 * 1536 * 4));
    float*          zbuf   = (float*)(ws + alloc((size_t)2 * 65 * 512 * 4));
    float*          midb   = (float*)(ws + alloc((size_t)2 * 65 * 2048 * 4));
    (void)ws_size; (void)in_sizes; (void)n_in; (void)out_size;

    // ---- DGCNN patch embed, point-major ----
    struct L { const float* w; const float* bn; int C; int O; int inOff; int outOff; };
    L ls[4] = {
        {w1, bn1, 3,   64,  0,   0},
        {w2, bn2, 64,  64,  0,   64},
        {w3, bn3, 64,  128, 64,  128},
        {w4, bn4, 128, 256, 128, 256},
    };
    for (int l = 0; l < 4; l++) {
        const L& P = ls[l];
        const float* xf;
        int lda; long long bstr;
        if (l == 0) { xf = x; lda = 3; bstr = (long long)2048 * 3; }
        else { xf = xcatF + P.inOff; lda = 512; bstr = (long long)2048 * 512; }

        xx_kernel<<<64, 256, 0, stream>>>(xf, xxb, P.C, lda, bstr);
        {
            dim3 g(2048 / 64, 2048 / 64, 2);
            gemm_nt_kernel<<<g, 256, 0, stream>>>(xf, xf, pdb, xxb,
                                                  2048, 2048, P.C, lda, lda, 2048,
                                                  bstr, bstr, (long long)2048 * 2048, 4);
        }
        topk_kernel<<<2 * 2048, 256, 0, stream>>>(pdb, idxb);
        wcat_kernel<<<(2 * P.O * P.C + 255) / 256, 256, 0, stream>>>(P.w, wcatF, wcatB, P.O, P.C);
        if (l == 0) {
            // K=3: fp32 NT gemm. Y[n][o2], o2 in [0,128)
            dim3 g(128 / 64, 2048 / 64, 2);
            gemm_nt_kernel<<<g, 256, 0, stream>>>(xf, wcatF, Yb, nullptr,
                                                  2048, 128, 3, 3, 3, 128,
                                                  bstr, 0, (long long)2048 * 128, 0);
        } else {
            dim3 g((2 * P.O) / 128, 2048 / 128, 2);
            mfma_nt_kernel<<<g, 256, 0, stream>>>(xcatB + P.inOff, wcatB, Yb, nullptr,
                                                  2 * P.O, P.C, 512, P.C, 2 * P.O,
                                                  (long long)2048 * 512, (long long)2048 * 2 * P.O, 0);
        }
        gather_max_kernel<<<(2 * 2048 * P.O + 255) / 256, 256, 0, stream>>>(
            Yb, idxb, P.bn, xcatF + P.outOff, xcatB + P.outOff, P.O);
    }

    // conv5 (bf16 MFMA): y5[n][o] = lrelu(bn5(xcat[n][:] . w5[o][:]))
    cast_kernel<<<(1024 * 512 + 255) / 256, 256, 0, stream>>>(w5, w5B, 1024 * 512);
    float* y5 = pdb;
    {
        dim3 g(1024 / 128, 2048 / 128, 2);
        mfma_nt_kernel<<<g, 256, 0, stream>>>(xcatB, w5B, y5, bn5,
                                              1024, 512, 512, 512, 1024,
                                              (long long)2048 * 512, (long long)2048 * 1024, 1);
    }
    pool_kernel<<<(2 * 64 * 1024 + 255) / 256, 256, 0, stream>>>(y5, hbuf);
    cls_kernel<<<(2 * 1024 + 255) / 256, 256, 0, stream>>>(cls, hbuf);

    // ---- transformer (fp32) ----
    float* Pbuf = pdb;
    for (int L = 0; L < 6; L++) {
        const float* ln1g = ln1 + (long long)L * 2048;
        const float* ln2g = ln2 + (long long)L * 2048;
        const float* wqkvL = wqkv + (long long)L * 1024 * 1536;
        const float* woL   = wo   + (long long)L * 512 * 1024;
        const float* boL   = bo   + (long long)L * 1024;
        const float* wf1L  = wf1  + (long long)L * 1024 * 2048;
        const float* bf1L  = bf1  + (long long)L * 2048;
        const float* wf2L  = wf2  + (long long)L * 2048 * 1024;
        const float* bf2L  = bf2  + (long long)L * 1024;

        ln_kernel<<<130, 256, 0, stream>>>(hbuf, pos, ln1g, ln1g + 1024, tbuf, 1);
        skinny(stream, tbuf, 1024, wqkvL, 1536, 1024, 16, Pbuf, qkvb, nullptr, 0);
        attn_kernel<<<dim3(65, 8, 2), 128, 0, stream>>>(qkvb, zbuf);
        skinny(stream, zbuf, 512, woL, 1024, 512, 16, Pbuf, hbuf, boL, 1);
        ln_kernel<<<130, 256, 0, stream>>>(hbuf, nullptr, ln2g, ln2g + 1024, tbuf, 0);
        skinny(stream, tbuf, 1024, wf1L, 2048, 1024, 16, Pbuf, midb, bf1L, 2);
        skinny(stream, midb, 2048, wf2L, 1024, 2048, 32, Pbuf, hbuf, bf2L, 1);
    }

    outcopy_kernel<<<(2 * 64 * 1024 + 255) / 256, 256, 0, stream>>>(hbuf, outp);
}